// Round 2
// baseline (3726.704 us; speedup 1.0000x reference)
//
#include <hip/hip_runtime.h>
#include <hip/hip_bf16.h>

#define B_  4
#define L_  2048      // LO == LQ == 2048
#define H_  128
#define NH_ 2
#define G_  10
#define NIN_ 41

// ---------------------------------------------------------------------------
// K1: query featurize + embed: xq_(256) = [t-feats(128), ch-feats(128)] * mq ;
//     qry_embed = xq_ @ w_qp + b_qp         grid: B*LQ blocks x 128 threads
// ---------------------------------------------------------------------------
__global__ __launch_bounds__(128)
void embed_q_kernel(const float* __restrict__ xq, const float* __restrict__ mq,
                    const float* __restrict__ w_q0, const float* __restrict__ b_q0,
                    const float* __restrict__ w_q1, const float* __restrict__ b_q1,
                    const float* __restrict__ w_cq, const float* __restrict__ b_cq,
                    const float* __restrict__ w_qp, const float* __restrict__ b_qp,
                    float* __restrict__ qe)
{
    const int row = blockIdx.x;           // b*L_ + q
    const int j   = threadIdx.x;          // 0..127
    __shared__ float feat[256];

    const float t   = xq[row * 2 + 0];
    const float chf = xq[row * 2 + 1];
    int ch = (int)chf; ch = max(0, min(NIN_ - 1, ch));   // safety clamp
    const float m   = mq[row];

    float tf;
    if (j == 0) tf = t * w_q0[0] + b_q0[0];
    else        tf = __sinf(t * w_q1[j - 1] + b_q1[j - 1]);
    feat[j] = tf * m;

    float cf = w_cq[ch * H_ + j] + b_cq[j];
    feat[128 + j] = fmaxf(cf, 0.f) * m;
    __syncthreads();

    float acc = b_qp[j];
    #pragma unroll 8
    for (int i = 0; i < 256; i++)
        acc += feat[i] * w_qp[i * H_ + j];
    qe[(size_t)row * H_ + j] = acc;
}

// ---------------------------------------------------------------------------
// K2: obs featurize + embed: obs_(257) = [t-feats(128), ch-feats(128), v]*mobs;
//     obs_embed = obs_ @ w_kp + b_kp       grid: B*LO blocks x 128 threads
// ---------------------------------------------------------------------------
__global__ __launch_bounds__(128)
void embed_obs_kernel(const float* __restrict__ obs, const float* __restrict__ mobs,
                      const float* __restrict__ w_o0, const float* __restrict__ b_o0,
                      const float* __restrict__ w_o1, const float* __restrict__ b_o1,
                      const float* __restrict__ w_cobs, const float* __restrict__ b_cobs,
                      const float* __restrict__ w_kp, const float* __restrict__ b_kp,
                      float* __restrict__ oe)
{
    const int row = blockIdx.x;
    const int j   = threadIdx.x;
    __shared__ float feat[257];

    const float t   = obs[row * 3 + 0];
    const float chf = obs[row * 3 + 1];
    const float xv  = obs[row * 3 + 2];
    int ch = (int)chf; ch = max(0, min(NIN_ - 1, ch));   // safety clamp
    const float m   = mobs[row];

    float tf;
    if (j == 0) tf = t * w_o0[0] + b_o0[0];
    else        tf = __sinf(t * w_o1[j - 1] + b_o1[j - 1]);
    feat[j] = tf * m;

    float cf = w_cobs[ch * H_ + j] + b_cobs[j];
    feat[128 + j] = fmaxf(cf, 0.f) * m;
    if (j == 0) feat[256] = xv * m;
    __syncthreads();

    float acc = b_kp[j];
    #pragma unroll 8
    for (int i = 0; i < 257; i++)
        acc += feat[i] * w_kp[i * H_ + j];
    oe[(size_t)row * H_ + j] = acc;
}

// ---------------------------------------------------------------------------
// K3: row GEMM (N,128)fp32 @ (128,256)fp32 + bias -> (N,256)fp32
// ---------------------------------------------------------------------------
__global__ __launch_bounds__(256)
void rowgemm_kernel(const float* __restrict__ X, const float* __restrict__ W,
                    const float* __restrict__ bias, float* __restrict__ Y)
{
    const int row = blockIdx.x;
    const int tid = threadIdx.x;
    __shared__ float xr[128];
    if (tid < 128) xr[tid] = X[(size_t)row * 128 + tid];
    __syncthreads();
    float acc = bias[tid];
    #pragma unroll 8
    for (int i = 0; i < 128; i++)
        acc += xr[i] * W[i * 256 + tid];
    Y[(size_t)row * 256 + tid] = acc;
}

// ---------------------------------------------------------------------------
// K4: attention core. Row layout (.., l, NH*H), head h at cols [h*128, h*128+128).
//     4 queries per block, two-pass LDS softmax.
//     score = -1e6 if mK[j]==0 or mQ[q]==0 (mQ may be null).
// ---------------------------------------------------------------------------
__global__ __launch_bounds__(256)
void attn_kernel(const float* __restrict__ Q, const float* __restrict__ KV,
                 const float* __restrict__ mQ, const float* __restrict__ mK,
                 float* __restrict__ O, int Lq, int q_bstride, int o_bstride)
{
    const int q0  = blockIdx.x * 4;
    const int h   = blockIdx.y;
    const int b   = blockIdx.z;
    const int tid = threadIdx.x;

    __shared__ float qtile[4][H_];
    __shared__ float sc[4][L_];         // 32 KB
    __shared__ float qmask[4];
    __shared__ float rowsum[4];

    for (int idx = tid; idx < 4 * H_; idx += 256) {
        const int qi = idx >> 7, d = idx & 127;
        const int q = q0 + qi;
        float v = 0.f;
        if (q < Lq) v = Q[(size_t)b * q_bstride + (size_t)q * (NH_ * H_) + h * H_ + d];
        qtile[qi][d] = v;
    }
    if (tid < 4) {
        const int q = q0 + tid;
        float m = 1.f;
        if (mQ != nullptr && q < Lq) m = mQ[b * Lq + q];
        qmask[tid] = m;
    }
    __syncthreads();

    const float scale = 0.088388347648318447f;   // 1/sqrt(128)
    for (int j = tid; j < L_; j += 256) {
        const float* kr = KV + ((size_t)b * L_ + j) * (NH_ * H_) + h * H_;
        float s0 = 0.f, s1 = 0.f, s2 = 0.f, s3 = 0.f;
        for (int d = 0; d < H_; d += 4) {
            const float4 k4 = *(const float4*)(kr + d);
            s0 += qtile[0][d] * k4.x + qtile[0][d+1] * k4.y + qtile[0][d+2] * k4.z + qtile[0][d+3] * k4.w;
            s1 += qtile[1][d] * k4.x + qtile[1][d+1] * k4.y + qtile[1][d+2] * k4.z + qtile[1][d+3] * k4.w;
            s2 += qtile[2][d] * k4.x + qtile[2][d+1] * k4.y + qtile[2][d+2] * k4.z + qtile[2][d+3] * k4.w;
            s3 += qtile[3][d] * k4.x + qtile[3][d+1] * k4.y + qtile[3][d+2] * k4.z + qtile[3][d+3] * k4.w;
        }
        const bool kz = (mK[b * L_ + j] == 0.f);
        sc[0][j] = (kz || qmask[0] == 0.f) ? -1000000.f : s0 * scale;
        sc[1][j] = (kz || qmask[1] == 0.f) ? -1000000.f : s1 * scale;
        sc[2][j] = (kz || qmask[2] == 0.f) ? -1000000.f : s2 * scale;
        sc[3][j] = (kz || qmask[3] == 0.f) ? -1000000.f : s3 * scale;
    }
    __syncthreads();

    // softmax: one 64-lane wave per query row
    {
        const int qi = tid >> 6;
        const int lane = tid & 63;
        float mx = -3.4e38f;
        for (int j = lane; j < L_; j += 64) mx = fmaxf(mx, sc[qi][j]);
        #pragma unroll
        for (int m = 32; m >= 1; m >>= 1) mx = fmaxf(mx, __shfl_xor(mx, m));
        float sum = 0.f;
        for (int j = lane; j < L_; j += 64) {
            const float e = __expf(sc[qi][j] - mx);
            sc[qi][j] = e;
            sum += e;
        }
        #pragma unroll
        for (int m = 32; m >= 1; m >>= 1) sum += __shfl_xor(sum, m);
        if (lane == 0) rowsum[qi] = sum;
    }
    __syncthreads();

    // V accumulation: threads = d(128) x query-group(2 groups of 2 queries)
    {
        const int d  = tid & 127;
        const int qg = tid >> 7;              // 0 or 1
        const float* vb = KV + (size_t)b * L_ * (NH_ * H_) + h * H_ + d;
        float a0 = 0.f, a1 = 0.f;
        #pragma unroll 4
        for (int j = 0; j < L_; j++) {
            const float v = vb[(size_t)j * (NH_ * H_)];
            a0 += sc[qg * 2 + 0][j] * v;
            a1 += sc[qg * 2 + 1][j] * v;
        }
        const int q = q0 + qg * 2;
        if (q < Lq)
            O[(size_t)b * o_bstride + (size_t)q * (NH_ * H_) + h * H_ + d] = a0 / rowsum[qg * 2 + 0];
        if (q + 1 < Lq)
            O[(size_t)b * o_bstride + (size_t)(q + 1) * (NH_ * H_) + h * H_ + d] = a1 / rowsum[qg * 2 + 1];
    }
}

// ---------------------------------------------------------------------------
// K5: output projection + residual (+ReLU): Y = relu?(R + A@W + b)
// ---------------------------------------------------------------------------
__global__ __launch_bounds__(128)
void outproj_kernel(const float* __restrict__ A, const float* __restrict__ R,
                    const float* __restrict__ W, const float* __restrict__ bias,
                    float* __restrict__ Y, int do_relu)
{
    const int row = blockIdx.x;
    const int tid = threadIdx.x;
    __shared__ float ar[256];
    ar[tid]       = A[(size_t)row * 256 + tid];
    ar[tid + 128] = A[(size_t)row * 256 + tid + 128];
    __syncthreads();
    float acc = R[(size_t)row * 128 + tid] + bias[tid];
    #pragma unroll 8
    for (int i = 0; i < 256; i++)
        acc += ar[i] * W[i * 128 + tid];
    if (do_relu) acc = fmaxf(acc, 0.f);
    Y[(size_t)row * 128 + tid] = acc;
}

// mw output projection: mw_ = mix_wt[g] + attn@ww_o + ww_ob ; grid B*G x 128
__global__ __launch_bounds__(128)
void mwproj_kernel(const float* __restrict__ A, const float* __restrict__ mixwt,
                   const float* __restrict__ W, const float* __restrict__ bias,
                   float* __restrict__ Y)
{
    const int bg  = blockIdx.x;       // b*10+g
    const int g   = bg % G_;
    const int tid = threadIdx.x;
    __shared__ float ar[256];
    ar[tid]       = A[(size_t)bg * 256 + tid];
    ar[tid + 128] = A[(size_t)bg * 256 + tid + 128];
    __syncthreads();
    float acc = mixwt[g * 128 + tid] + bias[tid];
    #pragma unroll 8
    for (int i = 0; i < 256; i++)
        acc += ar[i] * W[i * 128 + tid];
    Y[(size_t)bg * 128 + tid] = acc;
}

// mw final: z = mw_ @ w_mix + b_mix ; softmax over G ; write fp32. grid B x 64
__global__ __launch_bounds__(64)
void mwfinal_kernel(const float* __restrict__ MW, const float* __restrict__ wmix,
                    const float* __restrict__ bmix, float* __restrict__ out)
{
    const int b = blockIdx.x;
    const int g = threadIdx.x;
    __shared__ float z[16];
    if (g < G_) {
        float acc = bmix[0];
        for (int i = 0; i < 128; i++)
            acc += MW[((size_t)b * G_ + g) * 128 + i] * wmix[i];
        z[g] = acc;
    }
    __syncthreads();
    if (g == 0) {
        float mx = -3.4e38f;
        for (int i = 0; i < G_; i++) mx = fmaxf(mx, z[i]);
        float e[G_]; float s = 0.f;
        for (int i = 0; i < G_; i++) { e[i] = __expf(z[i] - mx); s += e[i]; }
        for (int i = 0; i < G_; i++) out[b * G_ + i] = e[i] / s;
    }
}

// K8: split GEMM (N,128)@(128,1280)+b, store transposed (B,G,LQ,H) fp32
__global__ __launch_bounds__(256)
void split_kernel(const float* __restrict__ X, const float* __restrict__ W,
                  const float* __restrict__ bias, float* __restrict__ out)
{
    const int row = blockIdx.x;        // b*2048+q
    const int b = row >> 11, q = row & 2047;
    const int tid = threadIdx.x;
    __shared__ float xr[128];
    if (tid < 128) xr[tid] = X[(size_t)row * 128 + tid];
    __syncthreads();
    for (int c = tid; c < 1280; c += 256) {
        float acc = bias[c];
        #pragma unroll 8
        for (int i = 0; i < 128; i++)
            acc += xr[i] * W[i * 1280 + c];
        const int g = c >> 7, hh = c & 127;
        out[(((size_t)(b * G_ + g)) * L_ + q) * H_ + hh] = acc;
    }
}

// ---------------------------------------------------------------------------
extern "C" void kernel_launch(void* const* d_in, const int* in_sizes, int n_in,
                              void* d_out, int out_size, void* d_ws, size_t ws_size,
                              hipStream_t stream)
{
    const float* obs    = (const float*)d_in[0];
    const float* mobs   = (const float*)d_in[1];
    const float* xq     = (const float*)d_in[2];
    const float* mq     = (const float*)d_in[3];
    const float* w_q0   = (const float*)d_in[4];
    const float* b_q0   = (const float*)d_in[5];
    const float* w_q1   = (const float*)d_in[6];
    const float* b_q1   = (const float*)d_in[7];
    const float* w_o0   = (const float*)d_in[8];
    const float* b_o0   = (const float*)d_in[9];
    const float* w_o1   = (const float*)d_in[10];
    const float* b_o1   = (const float*)d_in[11];
    const float* w_cobs = (const float*)d_in[12];
    const float* b_cobs = (const float*)d_in[13];
    const float* w_cq   = (const float*)d_in[14];
    const float* b_cq   = (const float*)d_in[15];
    const float* w_qp   = (const float*)d_in[16];
    const float* b_qp   = (const float*)d_in[17];
    const float* w_kp   = (const float*)d_in[18];
    const float* b_kp   = (const float*)d_in[19];
    const float* ws_q   = (const float*)d_in[20];
    const float* ws_qb  = (const float*)d_in[21];
    const float* ws_o   = (const float*)d_in[22];
    const float* ws_ob  = (const float*)d_in[23];
    const float* ww_q   = (const float*)d_in[24];
    const float* ww_qb  = (const float*)d_in[25];
    const float* ww_o   = (const float*)d_in[26];
    const float* ww_ob  = (const float*)d_in[27];
    const float* wc_q   = (const float*)d_in[28];
    const float* wc_qb  = (const float*)d_in[29];
    const float* wc_o   = (const float*)d_in[30];
    const float* wc_ob  = (const float*)d_in[31];
    const float* w_split= (const float*)d_in[32];
    const float* b_split= (const float*)d_in[33];
    const float* mix_wt = (const float*)d_in[34];
    const float* w_mix  = (const float*)d_in[35];
    const float* b_mix  = (const float*)d_in[36];

    float* out = (float*)d_out;
    char* ws  = (char*)d_ws;

    // workspace layout (fp32), ~36.4 MB total — bail cleanly if ws too small
    const size_t WS_NEEDED = ((size_t)36 << 20) + ((size_t)256 << 10);
    if (ws_size < WS_NEEDED) return;   // diagnostic: zeros output => ws too small

    const int NROW = B_ * L_;            // 8192
    float* qe    = (float*)(ws + 0);                       // 4 MB  (B,LQ,128)
    float* oe    = (float*)(ws + ((size_t)4  << 20));      // 4 MB  (B,LO,128) -> reused as x2
    float* kv    = (float*)(ws + ((size_t)8  << 20));      // 8 MB  (B,L,256)
    float* abuf  = (float*)(ws + ((size_t)16 << 20));      // 8 MB  self-attn out -> q_c
    float* x     = (float*)(ws + ((size_t)24 << 20));      // 4 MB  (B,L,128)
    float* abuf2 = (float*)(ws + ((size_t)28 << 20));      // 8 MB  cross-attn out
    float* qmw   = (float*)(ws + ((size_t)36 << 20));                      // (10,256)
    float* mwat  = (float*)(ws + ((size_t)36 << 20) + ((size_t)64 << 10)); // (B,10,256)
    float* mw_   = (float*)(ws + ((size_t)36 << 20) + ((size_t)128 << 10));// (B,10,128)
    float* x2    = oe;   // oe is dead after self-attn out-projection

    // 1-2: featurize + embed
    embed_q_kernel  <<<NROW, 128, 0, stream>>>(xq, mq, w_q0, b_q0, w_q1, b_q1,
                                               w_cq, b_cq, w_qp, b_qp, qe);
    embed_obs_kernel<<<NROW, 128, 0, stream>>>(obs, mobs, w_o0, b_o0, w_o1, b_o1,
                                               w_cobs, b_cobs, w_kp, b_kp, oe);

    // 3: self-attn shared q=k=v projection
    rowgemm_kernel<<<NROW, 256, 0, stream>>>(oe, ws_q, ws_qb, kv);

    // 4: self attention
    {
        dim3 g((L_ + 3) / 4, NH_, B_);
        attn_kernel<<<g, 256, 0, stream>>>(kv, kv, mobs, mobs, abuf,
                                           L_, L_ * 256, L_ * 256);
    }
    // 5: x = relu(oe + attn @ ws_o + ws_ob)
    outproj_kernel<<<NROW, 128, 0, stream>>>(abuf, oe, ws_o, ws_ob, x, 1);

    // 6-10: mixing-weights path (tiny)
    rowgemm_kernel<<<G_, 256, 0, stream>>>(mix_wt, ww_q, ww_qb, qmw);   // (10,256)
    rowgemm_kernel<<<NROW, 256, 0, stream>>>(x, ww_q, ww_qb, kv);       // kv_mw
    {
        dim3 g((G_ + 3) / 4, NH_, B_);
        attn_kernel<<<g, 256, 0, stream>>>(qmw, kv, nullptr, mobs, mwat,
                                           G_, 0, G_ * 256);
    }
    mwproj_kernel<<<B_ * G_, 128, 0, stream>>>(mwat, mix_wt, ww_o, ww_ob, mw_);
    mwfinal_kernel<<<B_, 64, 0, stream>>>(mw_, w_mix, b_mix,
                                          out + (size_t)B_ * G_ * L_ * H_);

    // 11-12: cross-attn projections (k==v share one projection)
    rowgemm_kernel<<<NROW, 256, 0, stream>>>(qe, wc_q, wc_qb, abuf);    // q_c
    rowgemm_kernel<<<NROW, 256, 0, stream>>>(x,  wc_q, wc_qb, kv);      // kv_c

    // 13: cross attention
    {
        dim3 g((L_ + 3) / 4, NH_, B_);
        attn_kernel<<<g, 256, 0, stream>>>(abuf, kv, mq, mobs, abuf2,
                                           L_, L_ * 256, L_ * 256);
    }
    // 14: x2 = relu(qe + attn2 @ wc_o + wc_ob)
    outproj_kernel<<<NROW, 128, 0, stream>>>(abuf2, qe, wc_o, wc_ob, x2, 1);

    // 15: split + transpose store
    split_kernel<<<NROW, 256, 0, stream>>>(x2, w_split, b_split, out);

    (void)in_sizes; (void)n_in; (void)out_size;
}

// Round 3
// 941.130 us; speedup vs baseline: 3.9598x; 3.9598x over previous
//
#include <hip/hip_runtime.h>
#include <hip/hip_bf16.h>

#define B_  4
#define L_  2048      // LO == LQ == 2048
#define H_  128
#define NH_ 2
#define G_  10
#define NIN_ 41

typedef __hip_bfloat16 bf16;
typedef __attribute__((ext_vector_type(8))) short bf16x8s;  // 8 bf16 = 4 VGPRs
typedef __attribute__((ext_vector_type(4))) float f32x4;

__device__ __forceinline__ unsigned short f2bf_bits(float x) {
    __hip_bfloat16 h = __float2bfloat16(x);
    return *reinterpret_cast<unsigned short*>(&h);
}

// ---------------------------------------------------------------------------
// K1: query featurize + embed
// ---------------------------------------------------------------------------
__global__ __launch_bounds__(128)
void embed_q_kernel(const float* __restrict__ xq, const float* __restrict__ mq,
                    const float* __restrict__ w_q0, const float* __restrict__ b_q0,
                    const float* __restrict__ w_q1, const float* __restrict__ b_q1,
                    const float* __restrict__ w_cq, const float* __restrict__ b_cq,
                    const float* __restrict__ w_qp, const float* __restrict__ b_qp,
                    float* __restrict__ qe)
{
    const int row = blockIdx.x;
    const int j   = threadIdx.x;
    __shared__ float feat[256];

    const float t   = xq[row * 2 + 0];
    const float chf = xq[row * 2 + 1];
    int ch = (int)chf; ch = max(0, min(NIN_ - 1, ch));
    const float m   = mq[row];

    float tf;
    if (j == 0) tf = t * w_q0[0] + b_q0[0];
    else        tf = __sinf(t * w_q1[j - 1] + b_q1[j - 1]);
    feat[j] = tf * m;

    float cf = w_cq[ch * H_ + j] + b_cq[j];
    feat[128 + j] = fmaxf(cf, 0.f) * m;
    __syncthreads();

    float acc = b_qp[j];
    #pragma unroll 8
    for (int i = 0; i < 256; i++)
        acc += feat[i] * w_qp[i * H_ + j];
    qe[(size_t)row * H_ + j] = acc;
}

// ---------------------------------------------------------------------------
// K2: obs featurize + embed
// ---------------------------------------------------------------------------
__global__ __launch_bounds__(128)
void embed_obs_kernel(const float* __restrict__ obs, const float* __restrict__ mobs,
                      const float* __restrict__ w_o0, const float* __restrict__ b_o0,
                      const float* __restrict__ w_o1, const float* __restrict__ b_o1,
                      const float* __restrict__ w_cobs, const float* __restrict__ b_cobs,
                      const float* __restrict__ w_kp, const float* __restrict__ b_kp,
                      float* __restrict__ oe)
{
    const int row = blockIdx.x;
    const int j   = threadIdx.x;
    __shared__ float feat[257];

    const float t   = obs[row * 3 + 0];
    const float chf = obs[row * 3 + 1];
    const float xv  = obs[row * 3 + 2];
    int ch = (int)chf; ch = max(0, min(NIN_ - 1, ch));
    const float m   = mobs[row];

    float tf;
    if (j == 0) tf = t * w_o0[0] + b_o0[0];
    else        tf = __sinf(t * w_o1[j - 1] + b_o1[j - 1]);
    feat[j] = tf * m;

    float cf = w_cobs[ch * H_ + j] + b_cobs[j];
    feat[128 + j] = fmaxf(cf, 0.f) * m;
    if (j == 0) feat[256] = xv * m;
    __syncthreads();

    float acc = b_kp[j];
    #pragma unroll 8
    for (int i = 0; i < 257; i++)
        acc += feat[i] * w_kp[i * H_ + j];
    oe[(size_t)row * H_ + j] = acc;
}

// ---------------------------------------------------------------------------
// K3a: row GEMM (N,128)fp32 @ (128,256)fp32 + bias -> (N,256)fp32
// ---------------------------------------------------------------------------
__global__ __launch_bounds__(256)
void rowgemm_kernel(const float* __restrict__ X, const float* __restrict__ W,
                    const float* __restrict__ bias, float* __restrict__ Y)
{
    const int row = blockIdx.x;
    const int tid = threadIdx.x;
    __shared__ float xr[128];
    if (tid < 128) xr[tid] = X[(size_t)row * 128 + tid];
    __syncthreads();
    float acc = bias[tid];
    #pragma unroll 8
    for (int i = 0; i < 128; i++)
        acc += xr[i] * W[i * 256 + tid];
    Y[(size_t)row * 256 + tid] = acc;
}

// ---------------------------------------------------------------------------
// K3b: row GEMM -> bf16 output in (B, NH, L, H) layout for flash attention
//      grid: B*L blocks x 256 threads ; blockIdx = b*L + l ; col = h*128+d
// ---------------------------------------------------------------------------
__global__ __launch_bounds__(256)
void rowgemm_bf16_kernel(const float* __restrict__ X, const float* __restrict__ W,
                         const float* __restrict__ bias, bf16* __restrict__ Y)
{
    const int row = blockIdx.x;            // b*L_ + l
    const int b = row >> 11, l = row & 2047;
    const int tid = threadIdx.x;
    __shared__ float xr[128];
    if (tid < 128) xr[tid] = X[(size_t)row * 128 + tid];
    __syncthreads();
    float acc = bias[tid];
    #pragma unroll 8
    for (int i = 0; i < 128; i++)
        acc += xr[i] * W[i * 256 + tid];
    const int h = tid >> 7, d = tid & 127;
    Y[(((size_t)(b * NH_ + h)) * L_ + l) * H_ + d] = __float2bfloat16(acc);
}

// ---------------------------------------------------------------------------
// K4: MFMA flash attention. Q,KV bf16 in (B,NH,L,H); O fp32 in (B,L,NH*H).
//     K == V (same buffer). mQ may be null. Full L x L, masked (-1e6).
//     Block: 256 thr = 4 waves x 16 queries = 64 q. Grid: (L/64, NH, B).
// ---------------------------------------------------------------------------
#define RMS_ 136    // KVrm row stride (ushorts), padded: bank-conflict-free
#define TS_  40     // KVT / P row stride (ushorts), padded

__global__ __launch_bounds__(256)
void flash_attn_kernel(const bf16* __restrict__ Qb, const bf16* __restrict__ KVb,
                       const float* __restrict__ mQ, const float* __restrict__ mK,
                       float* __restrict__ O)
{
    __shared__ unsigned short KVrm[32 * RMS_];   // [key][dim]   8704 B
    __shared__ unsigned short KVT [128 * TS_];   // [dim][key]  10240 B
    __shared__ unsigned short Ps  [4 * 16 * TS_];// per-wave P   5120 B
    __shared__ float kmrow[L_];                  //              8192 B
    __shared__ float qmv[64];

    const int tid  = threadIdx.x;
    const int lane = tid & 63;
    const int wave = tid >> 6;
    const int quad = lane >> 4;
    const int l15  = lane & 15;
    const int h = blockIdx.y, b = blockIdx.z;
    const int q0 = blockIdx.x * 64;

    for (int i = tid; i < L_; i += 256) kmrow[i] = mK[b * L_ + i];
    if (tid < 64) qmv[tid] = (mQ == nullptr) ? 1.f : mQ[b * L_ + q0 + tid];

    // Q fragments: A[m=q(lane&15)][k=d(quad*8+j)], 4 chunks of K=32
    const bf16* qrow = Qb + (((size_t)(b * NH_ + h)) * L_ + q0 + wave * 16 + l15) * H_;
    bf16x8s qf[4];
    #pragma unroll
    for (int kc = 0; kc < 4; kc++)
        qf[kc] = *(const bf16x8s*)(qrow + kc * 32 + quad * 8);

    float mo[4], li[4], qm[4];
    f32x4 Oacc[8];
    #pragma unroll
    for (int r = 0; r < 4; r++) { mo[r] = -1e30f; li[r] = 0.f; }
    #pragma unroll
    for (int c = 0; c < 8; c++) Oacc[c] = (f32x4){0.f, 0.f, 0.f, 0.f};
    __syncthreads();
    #pragma unroll
    for (int r = 0; r < 4; r++) qm[r] = qmv[wave * 16 + quad * 4 + r];

    const float SCALE = 0.08838834764831845f;    // 1/sqrt(128)
    const bf16* kvbase = KVb + (((size_t)(b * NH_ + h)) * L_) * H_;

    for (int k0 = 0; k0 < L_; k0 += 32) {
        __syncthreads();
        // ---- stage 32 x 128 KV tile: row-major + transposed ----
        {
            const int p  = tid >> 4;           // key pair 0..15
            const int d0 = (tid & 15) * 8;     // dim start
            const bf16* src = kvbase + (size_t)(k0 + 2 * p) * H_ + d0;
            uint4 va = *(const uint4*)(src);
            uint4 vb = *(const uint4*)(src + H_);
            *(uint4*)(&KVrm[(2 * p) * RMS_ + d0])     = va;
            *(uint4*)(&KVrm[(2 * p + 1) * RMS_ + d0]) = vb;
            const unsigned short* ka = (const unsigned short*)&va;
            const unsigned short* kb = (const unsigned short*)&vb;
            unsigned int* kt = (unsigned int*)KVT;
            #pragma unroll
            for (int i = 0; i < 8; i++)
                kt[(d0 + i) * (TS_ / 2) + p] = (unsigned int)ka[i] | ((unsigned int)kb[i] << 16);
        }
        __syncthreads();

        // ---- S = Q K^T  (16q x 32keys per wave) ----
        f32x4 s0a = (f32x4){0.f,0.f,0.f,0.f}, s1a = (f32x4){0.f,0.f,0.f,0.f};
        #pragma unroll
        for (int kc = 0; kc < 4; kc++) {
            bf16x8s k0f = *(bf16x8s*)(&KVrm[l15 * RMS_ + kc * 32 + quad * 8]);
            bf16x8s k1f = *(bf16x8s*)(&KVrm[(16 + l15) * RMS_ + kc * 32 + quad * 8]);
            s0a = __builtin_amdgcn_mfma_f32_16x16x32_bf16(qf[kc], k0f, s0a, 0, 0, 0);
            s1a = __builtin_amdgcn_mfma_f32_16x16x32_bf16(qf[kc], k1f, s1a, 0, 0, 0);
        }

        // ---- mask + scale; online softmax ----
        const float km0 = kmrow[k0 + l15];
        const float km1 = kmrow[k0 + 16 + l15];
        float s0[4], s1[4], mx[4];
        #pragma unroll
        for (int r = 0; r < 4; r++) {
            s0[r] = (km0 != 0.f && qm[r] != 0.f) ? s0a[r] * SCALE : -1000000.f;
            s1[r] = (km1 != 0.f && qm[r] != 0.f) ? s1a[r] * SCALE : -1000000.f;
            mx[r] = fmaxf(s0[r], s1[r]);
        }
        #pragma unroll
        for (int off = 1; off < 16; off <<= 1)
            #pragma unroll
            for (int r = 0; r < 4; r++) mx[r] = fmaxf(mx[r], __shfl_xor(mx[r], off));

        float p0[4], p1[4], rs[4], al[4];
        #pragma unroll
        for (int r = 0; r < 4; r++) {
            const float mn = fmaxf(mo[r], mx[r]);
            al[r] = __expf(mo[r] - mn);
            mo[r] = mn;
            p0[r] = __expf(s0[r] - mn);
            p1[r] = __expf(s1[r] - mn);
            rs[r] = p0[r] + p1[r];
        }
        #pragma unroll
        for (int off = 1; off < 16; off <<= 1)
            #pragma unroll
            for (int r = 0; r < 4; r++) rs[r] += __shfl_xor(rs[r], off);
        #pragma unroll
        for (int r = 0; r < 4; r++) li[r] = li[r] * al[r] + rs[r];
        #pragma unroll
        for (int c = 0; c < 8; c++)
            #pragma unroll
            for (int r = 0; r < 4; r++) Oacc[c][r] *= al[r];

        // ---- P -> LDS (bf16, row-major [q][key], stride TS_) ----
        unsigned short* pw = Ps + wave * 16 * TS_;
        #pragma unroll
        for (int r = 0; r < 4; r++) {
            pw[(quad * 4 + r) * TS_ + l15]      = f2bf_bits(p0[r]);
            pw[(quad * 4 + r) * TS_ + 16 + l15] = f2bf_bits(p1[r]);
        }
        // ---- O += P V  (A=P from LDS, B=V from KVT) ----
        bf16x8s pf = *(bf16x8s*)(&Ps[wave * 16 * TS_ + l15 * TS_ + quad * 8]);
        #pragma unroll
        for (int c = 0; c < 8; c++) {
            bf16x8s vf = *(bf16x8s*)(&KVT[(c * 16 + l15) * TS_ + quad * 8]);
            Oacc[c] = __builtin_amdgcn_mfma_f32_16x16x32_bf16(pf, vf, Oacc[c], 0, 0, 0);
        }
    }

    // ---- epilogue: O / l, write fp32 (B, L, NH*H) ----
    float* orow = O + ((size_t)b * L_ + q0 + wave * 16) * (NH_ * H_) + h * H_;
    #pragma unroll
    for (int r = 0; r < 4; r++) {
        const float inv = 1.f / li[r];
        #pragma unroll
        for (int c = 0; c < 8; c++)
            orow[(size_t)(quad * 4 + r) * (NH_ * H_) + c * 16 + l15] = Oacc[c][r] * inv;
    }
}

// ---------------------------------------------------------------------------
// K4b: old VALU attention — kept only for the tiny mixing-weights path (Lq=10)
// ---------------------------------------------------------------------------
__global__ __launch_bounds__(256)
void attn_kernel(const float* __restrict__ Q, const float* __restrict__ KV,
                 const float* __restrict__ mQ, const float* __restrict__ mK,
                 float* __restrict__ O, int Lq, int q_bstride, int o_bstride)
{
    const int q0  = blockIdx.x * 4;
    const int h   = blockIdx.y;
    const int b   = blockIdx.z;
    const int tid = threadIdx.x;

    __shared__ float qtile[4][H_];
    __shared__ float sc[4][L_];
    __shared__ float qmask[4];
    __shared__ float rowsum[4];

    for (int idx = tid; idx < 4 * H_; idx += 256) {
        const int qi = idx >> 7, d = idx & 127;
        const int q = q0 + qi;
        float v = 0.f;
        if (q < Lq) v = Q[(size_t)b * q_bstride + (size_t)q * (NH_ * H_) + h * H_ + d];
        qtile[qi][d] = v;
    }
    if (tid < 4) {
        const int q = q0 + tid;
        float m = 1.f;
        if (mQ != nullptr && q < Lq) m = mQ[b * Lq + q];
        qmask[tid] = m;
    }
    __syncthreads();

    const float scale = 0.088388347648318447f;
    for (int j = tid; j < L_; j += 256) {
        const float* kr = KV + ((size_t)b * L_ + j) * (NH_ * H_) + h * H_;
        float s0 = 0.f, s1 = 0.f, s2 = 0.f, s3 = 0.f;
        for (int d = 0; d < H_; d += 4) {
            const float4 k4 = *(const float4*)(kr + d);
            s0 += qtile[0][d] * k4.x + qtile[0][d+1] * k4.y + qtile[0][d+2] * k4.z + qtile[0][d+3] * k4.w;
            s1 += qtile[1][d] * k4.x + qtile[1][d+1] * k4.y + qtile[1][d+2] * k4.z + qtile[1][d+3] * k4.w;
            s2 += qtile[2][d] * k4.x + qtile[2][d+1] * k4.y + qtile[2][d+2] * k4.z + qtile[2][d+3] * k4.w;
            s3 += qtile[3][d] * k4.x + qtile[3][d+1] * k4.y + qtile[3][d+2] * k4.z + qtile[3][d+3] * k4.w;
        }
        const bool kz = (mK[b * L_ + j] == 0.f);
        sc[0][j] = (kz || qmask[0] == 0.f) ? -1000000.f : s0 * scale;
        sc[1][j] = (kz || qmask[1] == 0.f) ? -1000000.f : s1 * scale;
        sc[2][j] = (kz || qmask[2] == 0.f) ? -1000000.f : s2 * scale;
        sc[3][j] = (kz || qmask[3] == 0.f) ? -1000000.f : s3 * scale;
    }
    __syncthreads();

    {
        const int qi = tid >> 6;
        const int lane = tid & 63;
        float mx = -3.4e38f;
        for (int j = lane; j < L_; j += 64) mx = fmaxf(mx, sc[qi][j]);
        #pragma unroll
        for (int m = 32; m >= 1; m >>= 1) mx = fmaxf(mx, __shfl_xor(mx, m));
        float sum = 0.f;
        for (int j = lane; j < L_; j += 64) {
            const float e = __expf(sc[qi][j] - mx);
            sc[qi][j] = e;
            sum += e;
        }
        #pragma unroll
        for (int m = 32; m >= 1; m >>= 1) sum += __shfl_xor(sum, m);
        if (lane == 0) rowsum[qi] = sum;
    }
    __syncthreads();

    {
        const int d  = tid & 127;
        const int qg = tid >> 7;
        const float* vb = KV + (size_t)b * L_ * (NH_ * H_) + h * H_ + d;
        float a0 = 0.f, a1 = 0.f;
        #pragma unroll 4
        for (int j = 0; j < L_; j++) {
            const float v = vb[(size_t)j * (NH_ * H_)];
            a0 += sc[qg * 2 + 0][j] * v;
            a1 += sc[qg * 2 + 1][j] * v;
        }
        const int q = q0 + qg * 2;
        if (q < Lq)
            O[(size_t)b * o_bstride + (size_t)q * (NH_ * H_) + h * H_ + d] = a0 / rowsum[qg * 2 + 0];
        if (q + 1 < Lq)
            O[(size_t)b * o_bstride + (size_t)(q + 1) * (NH_ * H_) + h * H_ + d] = a1 / rowsum[qg * 2 + 1];
    }
}

// ---------------------------------------------------------------------------
// K5: output projection + residual (+ReLU)
// ---------------------------------------------------------------------------
__global__ __launch_bounds__(128)
void outproj_kernel(const float* __restrict__ A, const float* __restrict__ R,
                    const float* __restrict__ W, const float* __restrict__ bias,
                    float* __restrict__ Y, int do_relu)
{
    const int row = blockIdx.x;
    const int tid = threadIdx.x;
    __shared__ float ar[256];
    ar[tid]       = A[(size_t)row * 256 + tid];
    ar[tid + 128] = A[(size_t)row * 256 + tid + 128];
    __syncthreads();
    float acc = R[(size_t)row * 128 + tid] + bias[tid];
    #pragma unroll 8
    for (int i = 0; i < 256; i++)
        acc += ar[i] * W[i * 128 + tid];
    if (do_relu) acc = fmaxf(acc, 0.f);
    Y[(size_t)row * 128 + tid] = acc;
}

__global__ __launch_bounds__(128)
void mwproj_kernel(const float* __restrict__ A, const float* __restrict__ mixwt,
                   const float* __restrict__ W, const float* __restrict__ bias,
                   float* __restrict__ Y)
{
    const int bg  = blockIdx.x;
    const int g   = bg % G_;
    const int tid = threadIdx.x;
    __shared__ float ar[256];
    ar[tid]       = A[(size_t)bg * 256 + tid];
    ar[tid + 128] = A[(size_t)bg * 256 + tid + 128];
    __syncthreads();
    float acc = mixwt[g * 128 + tid] + bias[tid];
    #pragma unroll 8
    for (int i = 0; i < 256; i++)
        acc += ar[i] * W[i * 128 + tid];
    Y[(size_t)bg * 128 + tid] = acc;
}

__global__ __launch_bounds__(64)
void mwfinal_kernel(const float* __restrict__ MW, const float* __restrict__ wmix,
                    const float* __restrict__ bmix, float* __restrict__ out)
{
    const int b = blockIdx.x;
    const int g = threadIdx.x;
    __shared__ float z[16];
    if (g < G_) {
        float acc = bmix[0];
        for (int i = 0; i < 128; i++)
            acc += MW[((size_t)b * G_ + g) * 128 + i] * wmix[i];
        z[g] = acc;
    }
    __syncthreads();
    if (g == 0) {
        float mx = -3.4e38f;
        for (int i = 0; i < G_; i++) mx = fmaxf(mx, z[i]);
        float e[G_]; float s = 0.f;
        for (int i = 0; i < G_; i++) { e[i] = __expf(z[i] - mx); s += e[i]; }
        for (int i = 0; i < G_; i++) out[b * G_ + i] = e[i] / s;
    }
}

__global__ __launch_bounds__(256)
void split_kernel(const float* __restrict__ X, const float* __restrict__ W,
                  const float* __restrict__ bias, float* __restrict__ out)
{
    const int row = blockIdx.x;
    const int b = row >> 11, q = row & 2047;
    const int tid = threadIdx.x;
    __shared__ float xr[128];
    if (tid < 128) xr[tid] = X[(size_t)row * 128 + tid];
    __syncthreads();
    for (int c = tid; c < 1280; c += 256) {
        float acc = bias[c];
        #pragma unroll 8
        for (int i = 0; i < 128; i++)
            acc += xr[i] * W[i * 1280 + c];
        const int g = c >> 7, hh = c & 127;
        out[(((size_t)(b * G_ + g)) * L_ + q) * H_ + hh] = acc;
    }
}

// ---------------------------------------------------------------------------
extern "C" void kernel_launch(void* const* d_in, const int* in_sizes, int n_in,
                              void* d_out, int out_size, void* d_ws, size_t ws_size,
                              hipStream_t stream)
{
    const float* obs    = (const float*)d_in[0];
    const float* mobs   = (const float*)d_in[1];
    const float* xq     = (const float*)d_in[2];
    const float* mq     = (const float*)d_in[3];
    const float* w_q0   = (const float*)d_in[4];
    const float* b_q0   = (const float*)d_in[5];
    const float* w_q1   = (const float*)d_in[6];
    const float* b_q1   = (const float*)d_in[7];
    const float* w_o0   = (const float*)d_in[8];
    const float* b_o0   = (const float*)d_in[9];
    const float* w_o1   = (const float*)d_in[10];
    const float* b_o1   = (const float*)d_in[11];
    const float* w_cobs = (const float*)d_in[12];
    const float* b_cobs = (const float*)d_in[13];
    const float* w_cq   = (const float*)d_in[14];
    const float* b_cq   = (const float*)d_in[15];
    const float* w_qp   = (const float*)d_in[16];
    const float* b_qp   = (const float*)d_in[17];
    const float* w_kp   = (const float*)d_in[18];
    const float* b_kp   = (const float*)d_in[19];
    const float* ws_q   = (const float*)d_in[20];
    const float* ws_qb  = (const float*)d_in[21];
    const float* ws_o   = (const float*)d_in[22];
    const float* ws_ob  = (const float*)d_in[23];
    const float* ww_q   = (const float*)d_in[24];
    const float* ww_qb  = (const float*)d_in[25];
    const float* ww_o   = (const float*)d_in[26];
    const float* ww_ob  = (const float*)d_in[27];
    const float* wc_q   = (const float*)d_in[28];
    const float* wc_qb  = (const float*)d_in[29];
    const float* wc_o   = (const float*)d_in[30];
    const float* wc_ob  = (const float*)d_in[31];
    const float* w_split= (const float*)d_in[32];
    const float* b_split= (const float*)d_in[33];
    const float* mix_wt = (const float*)d_in[34];
    const float* w_mix  = (const float*)d_in[35];
    const float* b_mix  = (const float*)d_in[36];

    float* out = (float*)d_out;
    char* ws  = (char*)d_ws;

    const size_t MB = (size_t)1 << 20;
    const size_t WS_NEEDED = 32 * MB + (128 << 10);
    if (ws_size < WS_NEEDED) return;

    const int NROW = B_ * L_;
    float* qe    = (float*)(ws + 0);            // 4 MB (B,L,128)
    float* oe    = (float*)(ws + 4 * MB);       // 4 MB (B,L,128) -> x2
    bf16*  kvbs  = (bf16*) (ws + 8 * MB);       // 4 MB (B,NH,L,H) bf16 -> qcb
    float* abuf  = (float*)(ws + 12 * MB);      // 8 MB (B,L,256) -> kvcb (first 4 MB)
    float* x     = (float*)(ws + 20 * MB);      // 4 MB (B,L,128)
    float* kvf   = (float*)(ws + 24 * MB);      // 8 MB (B,L,256) mw path -> abuf2
    bf16*  qcb   = (bf16*) (ws + 8 * MB);       // reuse kvbs
    bf16*  kvcb  = (bf16*) (ws + 12 * MB);      // reuse abuf
    float* abuf2 = (float*)(ws + 24 * MB);      // reuse kvf
    float* x2    = oe;                          // reuse oe
    float* qmw   = (float*)(ws + 32 * MB);                   // (10,256)
    float* mwat  = (float*)(ws + 32 * MB + (16 << 10));      // (B,10,256)
    float* mw_   = (float*)(ws + 32 * MB + (64 << 10));      // (B,10,128)

    // 1-2: featurize + embed
    embed_q_kernel  <<<NROW, 128, 0, stream>>>(xq, mq, w_q0, b_q0, w_q1, b_q1,
                                               w_cq, b_cq, w_qp, b_qp, qe);
    embed_obs_kernel<<<NROW, 128, 0, stream>>>(obs, mobs, w_o0, b_o0, w_o1, b_o1,
                                               w_cobs, b_cobs, w_kp, b_kp, oe);

    // 3: self-attn shared q=k=v projection (bf16, per-head layout)
    rowgemm_bf16_kernel<<<NROW, 256, 0, stream>>>(oe, ws_q, ws_qb, kvbs);

    // 4: self attention (MFMA flash)
    {
        dim3 g(L_ / 64, NH_, B_);
        flash_attn_kernel<<<g, 256, 0, stream>>>(kvbs, kvbs, nullptr, mobs, abuf);
    }
    // 5: x = relu(oe + attn @ ws_o + ws_ob)
    outproj_kernel<<<NROW, 128, 0, stream>>>(abuf, oe, ws_o, ws_ob, x, 1);

    // 6-10: mixing-weights path (tiny, fp32)
    rowgemm_kernel<<<G_, 256, 0, stream>>>(mix_wt, ww_q, ww_qb, qmw);
    rowgemm_kernel<<<NROW, 256, 0, stream>>>(x, ww_q, ww_qb, kvf);
    {
        dim3 g((G_ + 3) / 4, NH_, B_);
        attn_kernel<<<g, 256, 0, stream>>>(qmw, kvf, nullptr, mobs, mwat,
                                           G_, 0, G_ * 256);
    }
    mwproj_kernel<<<B_ * G_, 128, 0, stream>>>(mwat, mix_wt, ww_o, ww_ob, mw_);
    mwfinal_kernel<<<B_, 64, 0, stream>>>(mw_, w_mix, b_mix,
                                          out + (size_t)B_ * G_ * L_ * H_);

    // 11-12: cross-attn projections (k==v share one projection), bf16
    rowgemm_bf16_kernel<<<NROW, 256, 0, stream>>>(qe, wc_q, wc_qb, qcb);
    rowgemm_bf16_kernel<<<NROW, 256, 0, stream>>>(x,  wc_q, wc_qb, kvcb);

    // 13: cross attention (MFMA flash)
    {
        dim3 g(L_ / 64, NH_, B_);
        flash_attn_kernel<<<g, 256, 0, stream>>>(qcb, kvcb, mq, mobs, abuf2);
    }
    // 14: x2 = relu(qe + attn2 @ wc_o + wc_ob)
    outproj_kernel<<<NROW, 128, 0, stream>>>(abuf2, qe, wc_o, wc_ob, x2, 1);

    // 15: split + transpose store
    split_kernel<<<NROW, 256, 0, stream>>>(x2, w_split, b_split, out);

    (void)in_sizes; (void)n_in; (void)out_size;
}

// Round 4
// 677.301 us; speedup vs baseline: 5.5023x; 1.3895x over previous
//
#include <hip/hip_runtime.h>
#include <hip/hip_bf16.h>

#define B_  4
#define L_  2048      // LO == LQ == 2048
#define H_  128
#define NH_ 2
#define G_  10
#define NIN_ 41

typedef __hip_bfloat16 bf16;
typedef __attribute__((ext_vector_type(8))) short bf16x8s;  // 8 bf16 = 4 VGPRs
typedef __attribute__((ext_vector_type(4))) float f32x4;

__device__ __forceinline__ unsigned short f2bf_bits(float x) {
    __hip_bfloat16 h = __float2bfloat16(x);
    return *reinterpret_cast<unsigned short*>(&h);
}

// ---------------------------------------------------------------------------
// K1: query featurize + embed (fp32 + bf16 outputs)
// ---------------------------------------------------------------------------
__global__ __launch_bounds__(128)
void embed_q_kernel(const float* __restrict__ xq, const float* __restrict__ mq,
                    const float* __restrict__ w_q0, const float* __restrict__ b_q0,
                    const float* __restrict__ w_q1, const float* __restrict__ b_q1,
                    const float* __restrict__ w_cq, const float* __restrict__ b_cq,
                    const float* __restrict__ w_qp, const float* __restrict__ b_qp,
                    float* __restrict__ qe, bf16* __restrict__ qe_bf)
{
    const int row = blockIdx.x;
    const int j   = threadIdx.x;
    __shared__ float feat[256];

    const float t   = xq[row * 2 + 0];
    const float chf = xq[row * 2 + 1];
    int ch = (int)chf; ch = max(0, min(NIN_ - 1, ch));
    const float m   = mq[row];

    float tf;
    if (j == 0) tf = t * w_q0[0] + b_q0[0];
    else        tf = __sinf(t * w_q1[j - 1] + b_q1[j - 1]);
    feat[j] = tf * m;

    float cf = w_cq[ch * H_ + j] + b_cq[j];
    feat[128 + j] = fmaxf(cf, 0.f) * m;
    __syncthreads();

    float acc = b_qp[j];
    #pragma unroll 8
    for (int i = 0; i < 256; i++)
        acc += feat[i] * w_qp[i * H_ + j];
    qe[(size_t)row * H_ + j] = acc;
    qe_bf[(size_t)row * H_ + j] = __float2bfloat16(acc);
}

// ---------------------------------------------------------------------------
// K2: obs featurize + embed (fp32 + bf16 outputs)
// ---------------------------------------------------------------------------
__global__ __launch_bounds__(128)
void embed_obs_kernel(const float* __restrict__ obs, const float* __restrict__ mobs,
                      const float* __restrict__ w_o0, const float* __restrict__ b_o0,
                      const float* __restrict__ w_o1, const float* __restrict__ b_o1,
                      const float* __restrict__ w_cobs, const float* __restrict__ b_cobs,
                      const float* __restrict__ w_kp, const float* __restrict__ b_kp,
                      float* __restrict__ oe, bf16* __restrict__ oe_bf)
{
    const int row = blockIdx.x;
    const int j   = threadIdx.x;
    __shared__ float feat[257];

    const float t   = obs[row * 3 + 0];
    const float chf = obs[row * 3 + 1];
    const float xv  = obs[row * 3 + 2];
    int ch = (int)chf; ch = max(0, min(NIN_ - 1, ch));
    const float m   = mobs[row];

    float tf;
    if (j == 0) tf = t * w_o0[0] + b_o0[0];
    else        tf = __sinf(t * w_o1[j - 1] + b_o1[j - 1]);
    feat[j] = tf * m;

    float cf = w_cobs[ch * H_ + j] + b_cobs[j];
    feat[128 + j] = fmaxf(cf, 0.f) * m;
    if (j == 0) feat[256] = xv * m;
    __syncthreads();

    float acc = b_kp[j];
    #pragma unroll 8
    for (int i = 0; i < 257; i++)
        acc += feat[i] * w_kp[i * H_ + j];
    oe[(size_t)row * H_ + j] = acc;
    oe_bf[(size_t)row * H_ + j] = __float2bfloat16(acc);
}

// ---------------------------------------------------------------------------
// Weight transpose + bf16 convert: WT[n*K+k] = W[k*N+n]. grid N x K threads
// ---------------------------------------------------------------------------
__global__ void wtrans_kernel(const float* __restrict__ W, bf16* __restrict__ WT,
                              int K, int N)
{
    const int n = blockIdx.x, k = threadIdx.x;
    WT[(size_t)n * K + k] = __float2bfloat16(W[(size_t)k * N + n]);
}

// ---------------------------------------------------------------------------
// Generic MFMA GEMM: C = A(bf16 M x K) @ W(bf16, stored as WT N x K) + bias
// optional fp32 residual R (M x N) added pre-ReLU. 64x64 tile, 4 waves.
// out modes: 0 = fp32 row-major, 1 = bf16 row-major,
//            2 = bf16 per-head (B,NH,L,H) [n = h*128+d, m = b*L+l],
//            3 = fp32 split-transposed (B,G,L,H) [n = g*128+hh, m = b*L+q]
// grid (M/64, N/64) x 256 threads.
// ---------------------------------------------------------------------------
__global__ __launch_bounds__(256)
void gemm_kernel(const bf16* __restrict__ A, const bf16* __restrict__ WT,
                 const float* __restrict__ bias, const float* __restrict__ R,
                 void* __restrict__ out, int K, int N, int mode, int do_relu)
{
    const int wave = threadIdx.x >> 6, lane = threadIdx.x & 63;
    const int quad = lane >> 4, l15 = lane & 15;
    const int m0 = blockIdx.x * 64 + wave * 16;
    const int n0 = blockIdx.y * 64;

    f32x4 acc[4];
    #pragma unroll
    for (int c = 0; c < 4; c++) acc[c] = (f32x4){0.f, 0.f, 0.f, 0.f};

    const bf16* arow = A + (size_t)(m0 + l15) * K;
    #pragma unroll 4
    for (int kc = 0; kc < K; kc += 32) {
        bf16x8s af = *(const bf16x8s*)(arow + kc + quad * 8);
        #pragma unroll
        for (int c = 0; c < 4; c++) {
            bf16x8s wf = *(const bf16x8s*)(WT + (size_t)(n0 + c * 16 + l15) * K + kc + quad * 8);
            acc[c] = __builtin_amdgcn_mfma_f32_16x16x32_bf16(af, wf, acc[c], 0, 0, 0);
        }
    }

    #pragma unroll
    for (int c = 0; c < 4; c++) {
        const int n = n0 + c * 16 + l15;
        const float bv = bias[n];
        #pragma unroll
        for (int r = 0; r < 4; r++) {
            const int m = m0 + quad * 4 + r;
            float v = acc[c][r] + bv;
            if (R != nullptr) v += R[(size_t)m * N + n];
            if (do_relu) v = fmaxf(v, 0.f);
            if (mode == 0) {
                ((float*)out)[(size_t)m * N + n] = v;
            } else if (mode == 1) {
                ((bf16*)out)[(size_t)m * N + n] = __float2bfloat16(v);
            } else if (mode == 2) {
                const int b = m >> 11, l = m & 2047, hh = n >> 7, d = n & 127;
                ((bf16*)out)[(((size_t)(b * NH_ + hh)) * L_ + l) * H_ + d] = __float2bfloat16(v);
            } else {
                const int b = m >> 11, q = m & 2047, g = n >> 7, hh = n & 127;
                ((float*)out)[(((size_t)(b * G_ + g)) * L_ + q) * H_ + hh] = v;
            }
        }
    }
}

// ---------------------------------------------------------------------------
// K4: MFMA flash attention. Q,KV bf16 in (B,NH,L,H); O bf16 in (B,L,NH*H).
//     K == V (same buffer). mQ may be null. Full L x L, masked (-1e6).
//     Block: 256 thr = 4 waves x 16 queries = 64 q. Grid: (L/64, NH, B).
// ---------------------------------------------------------------------------
#define RMS_ 136    // KVrm row stride (ushorts), padded
#define TS_  40     // KVT / P row stride (ushorts), padded

__global__ __launch_bounds__(256)
void flash_attn_kernel(const bf16* __restrict__ Qb, const bf16* __restrict__ KVb,
                       const float* __restrict__ mQ, const float* __restrict__ mK,
                       bf16* __restrict__ O)
{
    __shared__ unsigned short KVrm[32 * RMS_];
    __shared__ unsigned short KVT [128 * TS_];
    __shared__ unsigned short Ps  [4 * 16 * TS_];
    __shared__ float kmrow[L_];
    __shared__ float qmv[64];

    const int tid  = threadIdx.x;
    const int lane = tid & 63;
    const int wave = tid >> 6;
    const int quad = lane >> 4;
    const int l15  = lane & 15;
    const int h = blockIdx.y, b = blockIdx.z;
    const int q0 = blockIdx.x * 64;

    for (int i = tid; i < L_; i += 256) kmrow[i] = mK[b * L_ + i];
    if (tid < 64) qmv[tid] = (mQ == nullptr) ? 1.f : mQ[b * L_ + q0 + tid];

    const bf16* qrow = Qb + (((size_t)(b * NH_ + h)) * L_ + q0 + wave * 16 + l15) * H_;
    bf16x8s qf[4];
    #pragma unroll
    for (int kc = 0; kc < 4; kc++)
        qf[kc] = *(const bf16x8s*)(qrow + kc * 32 + quad * 8);

    float mo[4], li[4], qm[4];
    f32x4 Oacc[8];
    #pragma unroll
    for (int r = 0; r < 4; r++) { mo[r] = -1e30f; li[r] = 0.f; }
    #pragma unroll
    for (int c = 0; c < 8; c++) Oacc[c] = (f32x4){0.f, 0.f, 0.f, 0.f};
    __syncthreads();
    #pragma unroll
    for (int r = 0; r < 4; r++) qm[r] = qmv[wave * 16 + quad * 4 + r];

    const float SCALE = 0.08838834764831845f;
    const bf16* kvbase = KVb + (((size_t)(b * NH_ + h)) * L_) * H_;

    for (int k0 = 0; k0 < L_; k0 += 32) {
        __syncthreads();
        {
            const int p  = tid >> 4;
            const int d0 = (tid & 15) * 8;
            const bf16* src = kvbase + (size_t)(k0 + 2 * p) * H_ + d0;
            uint4 va = *(const uint4*)(src);
            uint4 vb = *(const uint4*)(src + H_);
            *(uint4*)(&KVrm[(2 * p) * RMS_ + d0])     = va;
            *(uint4*)(&KVrm[(2 * p + 1) * RMS_ + d0]) = vb;
            const unsigned short* ka = (const unsigned short*)&va;
            const unsigned short* kb = (const unsigned short*)&vb;
            unsigned int* kt = (unsigned int*)KVT;
            #pragma unroll
            for (int i = 0; i < 8; i++)
                kt[(d0 + i) * (TS_ / 2) + p] = (unsigned int)ka[i] | ((unsigned int)kb[i] << 16);
        }
        __syncthreads();

        f32x4 s0a = (f32x4){0.f,0.f,0.f,0.f}, s1a = (f32x4){0.f,0.f,0.f,0.f};
        #pragma unroll
        for (int kc = 0; kc < 4; kc++) {
            bf16x8s k0f = *(bf16x8s*)(&KVrm[l15 * RMS_ + kc * 32 + quad * 8]);
            bf16x8s k1f = *(bf16x8s*)(&KVrm[(16 + l15) * RMS_ + kc * 32 + quad * 8]);
            s0a = __builtin_amdgcn_mfma_f32_16x16x32_bf16(qf[kc], k0f, s0a, 0, 0, 0);
            s1a = __builtin_amdgcn_mfma_f32_16x16x32_bf16(qf[kc], k1f, s1a, 0, 0, 0);
        }

        const float km0 = kmrow[k0 + l15];
        const float km1 = kmrow[k0 + 16 + l15];
        float s0[4], s1[4], mx[4];
        #pragma unroll
        for (int r = 0; r < 4; r++) {
            s0[r] = (km0 != 0.f && qm[r] != 0.f) ? s0a[r] * SCALE : -1000000.f;
            s1[r] = (km1 != 0.f && qm[r] != 0.f) ? s1a[r] * SCALE : -1000000.f;
            mx[r] = fmaxf(s0[r], s1[r]);
        }
        #pragma unroll
        for (int off = 1; off < 16; off <<= 1)
            #pragma unroll
            for (int r = 0; r < 4; r++) mx[r] = fmaxf(mx[r], __shfl_xor(mx[r], off));

        float p0[4], p1[4], rs[4], al[4];
        #pragma unroll
        for (int r = 0; r < 4; r++) {
            const float mn = fmaxf(mo[r], mx[r]);
            al[r] = __expf(mo[r] - mn);
            mo[r] = mn;
            p0[r] = __expf(s0[r] - mn);
            p1[r] = __expf(s1[r] - mn);
            rs[r] = p0[r] + p1[r];
        }
        #pragma unroll
        for (int off = 1; off < 16; off <<= 1)
            #pragma unroll
            for (int r = 0; r < 4; r++) rs[r] += __shfl_xor(rs[r], off);
        #pragma unroll
        for (int r = 0; r < 4; r++) li[r] = li[r] * al[r] + rs[r];
        #pragma unroll
        for (int c = 0; c < 8; c++)
            #pragma unroll
            for (int r = 0; r < 4; r++) Oacc[c][r] *= al[r];

        unsigned short* pw = Ps + wave * 16 * TS_;
        #pragma unroll
        for (int r = 0; r < 4; r++) {
            pw[(quad * 4 + r) * TS_ + l15]      = f2bf_bits(p0[r]);
            pw[(quad * 4 + r) * TS_ + 16 + l15] = f2bf_bits(p1[r]);
        }
        bf16x8s pf = *(bf16x8s*)(&Ps[wave * 16 * TS_ + l15 * TS_ + quad * 8]);
        #pragma unroll
        for (int c = 0; c < 8; c++) {
            bf16x8s vf = *(bf16x8s*)(&KVT[(c * 16 + l15) * TS_ + quad * 8]);
            Oacc[c] = __builtin_amdgcn_mfma_f32_16x16x32_bf16(pf, vf, Oacc[c], 0, 0, 0);
        }
    }

    bf16* orow = O + ((size_t)b * L_ + q0 + wave * 16) * (NH_ * H_) + h * H_;
    #pragma unroll
    for (int r = 0; r < 4; r++) {
        const float inv = 1.f / li[r];
        #pragma unroll
        for (int c = 0; c < 8; c++)
            orow[(size_t)(quad * 4 + r) * (NH_ * H_) + c * 16 + l15] =
                __float2bfloat16(Oacc[c][r] * inv);
    }
}

// ---------------------------------------------------------------------------
// VALU attention — only for the tiny mixing-weights path (Lq=10)
// ---------------------------------------------------------------------------
__global__ __launch_bounds__(256)
void attn_kernel(const float* __restrict__ Q, const float* __restrict__ KV,
                 const float* __restrict__ mQ, const float* __restrict__ mK,
                 float* __restrict__ O, int Lq, int q_bstride, int o_bstride)
{
    const int q0  = blockIdx.x * 4;
    const int h   = blockIdx.y;
    const int b   = blockIdx.z;
    const int tid = threadIdx.x;

    __shared__ float qtile[4][H_];
    __shared__ float sc[4][L_];
    __shared__ float qmask[4];
    __shared__ float rowsum[4];

    for (int idx = tid; idx < 4 * H_; idx += 256) {
        const int qi = idx >> 7, d = idx & 127;
        const int q = q0 + qi;
        float v = 0.f;
        if (q < Lq) v = Q[(size_t)b * q_bstride + (size_t)q * (NH_ * H_) + h * H_ + d];
        qtile[qi][d] = v;
    }
    if (tid < 4) {
        const int q = q0 + tid;
        float m = 1.f;
        if (mQ != nullptr && q < Lq) m = mQ[b * Lq + q];
        qmask[tid] = m;
    }
    __syncthreads();

    const float scale = 0.088388347648318447f;
    for (int j = tid; j < L_; j += 256) {
        const float* kr = KV + ((size_t)b * L_ + j) * (NH_ * H_) + h * H_;
        float s0 = 0.f, s1 = 0.f, s2 = 0.f, s3 = 0.f;
        for (int d = 0; d < H_; d += 4) {
            const float4 k4 = *(const float4*)(kr + d);
            s0 += qtile[0][d] * k4.x + qtile[0][d+1] * k4.y + qtile[0][d+2] * k4.z + qtile[0][d+3] * k4.w;
            s1 += qtile[1][d] * k4.x + qtile[1][d+1] * k4.y + qtile[1][d+2] * k4.z + qtile[1][d+3] * k4.w;
            s2 += qtile[2][d] * k4.x + qtile[2][d+1] * k4.y + qtile[2][d+2] * k4.z + qtile[2][d+3] * k4.w;
            s3 += qtile[3][d] * k4.x + qtile[3][d+1] * k4.y + qtile[3][d+2] * k4.z + qtile[3][d+3] * k4.w;
        }
        const bool kz = (mK[b * L_ + j] == 0.f);
        sc[0][j] = (kz || qmask[0] == 0.f) ? -1000000.f : s0 * scale;
        sc[1][j] = (kz || qmask[1] == 0.f) ? -1000000.f : s1 * scale;
        sc[2][j] = (kz || qmask[2] == 0.f) ? -1000000.f : s2 * scale;
        sc[3][j] = (kz || qmask[3] == 0.f) ? -1000000.f : s3 * scale;
    }
    __syncthreads();

    {
        const int qi = tid >> 6;
        const int lane = tid & 63;
        float mx = -3.4e38f;
        for (int j = lane; j < L_; j += 64) mx = fmaxf(mx, sc[qi][j]);
        #pragma unroll
        for (int m = 32; m >= 1; m >>= 1) mx = fmaxf(mx, __shfl_xor(mx, m));
        float sum = 0.f;
        for (int j = lane; j < L_; j += 64) {
            const float e = __expf(sc[qi][j] - mx);
            sc[qi][j] = e;
            sum += e;
        }
        #pragma unroll
        for (int m = 32; m >= 1; m >>= 1) sum += __shfl_xor(sum, m);
        if (lane == 0) rowsum[qi] = sum;
    }
    __syncthreads();

    {
        const int d  = tid & 127;
        const int qg = tid >> 7;
        const float* vb = KV + (size_t)b * L_ * (NH_ * H_) + h * H_ + d;
        float a0 = 0.f, a1 = 0.f;
        #pragma unroll 4
        for (int j = 0; j < L_; j++) {
            const float v = vb[(size_t)j * (NH_ * H_)];
            a0 += sc[qg * 2 + 0][j] * v;
            a1 += sc[qg * 2 + 1][j] * v;
        }
        const int q = q0 + qg * 2;
        if (q < Lq)
            O[(size_t)b * o_bstride + (size_t)q * (NH_ * H_) + h * H_ + d] = a0 / rowsum[qg * 2 + 0];
        if (q + 1 < Lq)
            O[(size_t)b * o_bstride + (size_t)(q + 1) * (NH_ * H_) + h * H_ + d] = a1 / rowsum[qg * 2 + 1];
    }
}

// scalar row GEMM for the tiny qmw (10 rows)
__global__ __launch_bounds__(256)
void rowgemm_kernel(const float* __restrict__ X, const float* __restrict__ W,
                    const float* __restrict__ bias, float* __restrict__ Y)
{
    const int row = blockIdx.x;
    const int tid = threadIdx.x;
    __shared__ float xr[128];
    if (tid < 128) xr[tid] = X[(size_t)row * 128 + tid];
    __syncthreads();
    float acc = bias[tid];
    #pragma unroll 8
    for (int i = 0; i < 128; i++)
        acc += xr[i] * W[i * 256 + tid];
    Y[(size_t)row * 256 + tid] = acc;
}

__global__ __launch_bounds__(128)
void mwproj_kernel(const float* __restrict__ A, const float* __restrict__ mixwt,
                   const float* __restrict__ W, const float* __restrict__ bias,
                   float* __restrict__ Y)
{
    const int bg  = blockIdx.x;
    const int g   = bg % G_;
    const int tid = threadIdx.x;
    __shared__ float ar[256];
    ar[tid]       = A[(size_t)bg * 256 + tid];
    ar[tid + 128] = A[(size_t)bg * 256 + tid + 128];
    __syncthreads();
    float acc = mixwt[g * 128 + tid] + bias[tid];
    #pragma unroll 8
    for (int i = 0; i < 256; i++)
        acc += ar[i] * W[i * 128 + tid];
    Y[(size_t)bg * 128 + tid] = acc;
}

__global__ __launch_bounds__(64)
void mwfinal_kernel(const float* __restrict__ MW, const float* __restrict__ wmix,
                    const float* __restrict__ bmix, float* __restrict__ out)
{
    const int b = blockIdx.x;
    const int g = threadIdx.x;
    __shared__ float z[16];
    if (g < G_) {
        float acc = bmix[0];
        for (int i = 0; i < 128; i++)
            acc += MW[((size_t)b * G_ + g) * 128 + i] * wmix[i];
        z[g] = acc;
    }
    __syncthreads();
    if (g == 0) {
        float mx = -3.4e38f;
        for (int i = 0; i < G_; i++) mx = fmaxf(mx, z[i]);
        float e[G_]; float s = 0.f;
        for (int i = 0; i < G_; i++) { e[i] = __expf(z[i] - mx); s += e[i]; }
        for (int i = 0; i < G_; i++) out[b * G_ + i] = e[i] / s;
    }
}

// ---------------------------------------------------------------------------
extern "C" void kernel_launch(void* const* d_in, const int* in_sizes, int n_in,
                              void* d_out, int out_size, void* d_ws, size_t ws_size,
                              hipStream_t stream)
{
    const float* obs    = (const float*)d_in[0];
    const float* mobs   = (const float*)d_in[1];
    const float* xq     = (const float*)d_in[2];
    const float* mq     = (const float*)d_in[3];
    const float* w_q0   = (const float*)d_in[4];
    const float* b_q0   = (const float*)d_in[5];
    const float* w_q1   = (const float*)d_in[6];
    const float* b_q1   = (const float*)d_in[7];
    const float* w_o0   = (const float*)d_in[8];
    const float* b_o0   = (const float*)d_in[9];
    const float* w_o1   = (const float*)d_in[10];
    const float* b_o1   = (const float*)d_in[11];
    const float* w_cobs = (const float*)d_in[12];
    const float* b_cobs = (const float*)d_in[13];
    const float* w_cq   = (const float*)d_in[14];
    const float* b_cq   = (const float*)d_in[15];
    const float* w_qp   = (const float*)d_in[16];
    const float* b_qp   = (const float*)d_in[17];
    const float* w_kp   = (const float*)d_in[18];
    const float* b_kp   = (const float*)d_in[19];
    const float* ws_q   = (const float*)d_in[20];
    const float* ws_qb  = (const float*)d_in[21];
    const float* ws_o   = (const float*)d_in[22];
    const float* ws_ob  = (const float*)d_in[23];
    const float* ww_q   = (const float*)d_in[24];
    const float* ww_qb  = (const float*)d_in[25];
    const float* ww_o   = (const float*)d_in[26];
    const float* ww_ob  = (const float*)d_in[27];
    const float* wc_q   = (const float*)d_in[28];
    const float* wc_qb  = (const float*)d_in[29];
    const float* wc_o   = (const float*)d_in[30];
    const float* wc_ob  = (const float*)d_in[31];
    const float* w_split= (const float*)d_in[32];
    const float* b_split= (const float*)d_in[33];
    const float* mix_wt = (const float*)d_in[34];
    const float* w_mix  = (const float*)d_in[35];
    const float* b_mix  = (const float*)d_in[36];

    float* out = (float*)d_out;
    char* ws  = (char*)d_ws;

    const size_t MB = (size_t)1 << 20;
    const size_t KB = (size_t)1 << 10;
    const size_t WS_NEEDED = 31 * MB;
    if (ws_size < WS_NEEDED) return;

    const int NROW = B_ * L_;          // 8192
    // workspace (30.8 MB)
    float* qe    = (float*)(ws + 0);            // 4 MB fp32 (residual cross)
    float* oe    = (float*)(ws + 4 * MB);       // 4 MB fp32 (residual self)
    bf16*  qe_bf = (bf16*) (ws + 8 * MB);       // 2 MB
    bf16*  oe_bf = (bf16*) (ws + 10 * MB);      // 2 MB -> x2_bf later
    bf16*  kvbs  = (bf16*) (ws + 12 * MB);      // 4 MB -> qcb later
    bf16*  abuf  = (bf16*) (ws + 16 * MB);      // 4 MB -> kvcb later
    bf16*  x_bf  = (bf16*) (ws + 20 * MB);      // 2 MB
    float* kvf   = (float*)(ws + 22 * MB);      // 8 MB -> abuf2 (4 MB) later
    bf16*  qcb   = (bf16*) (ws + 12 * MB);
    bf16*  kvcb  = (bf16*) (ws + 16 * MB);
    bf16*  abuf2 = (bf16*) (ws + 22 * MB);
    bf16*  x2_bf = (bf16*) (ws + 10 * MB);
    bf16*  wsqT  = (bf16*) (ws + 30 * MB);              // 64 KB (256x128)
    bf16*  wsoT  = (bf16*) (ws + 30 * MB + 64 * KB);    // 64 KB (128x256)
    bf16*  wwqT  = (bf16*) (ws + 30 * MB + 128 * KB);   // 64 KB
    bf16*  wcqT  = (bf16*) (ws + 30 * MB + 192 * KB);   // 64 KB
    bf16*  wcoT  = (bf16*) (ws + 30 * MB + 256 * KB);   // 64 KB
    bf16*  wsplT = (bf16*) (ws + 30 * MB + 320 * KB);   // 320 KB (1280x128)
    float* qmw   = (float*)(ws + 30 * MB + 640 * KB);   // 10 KB
    float* mwat  = (float*)(ws + 30 * MB + 656 * KB);   // 40 KB
    float* mw_   = (float*)(ws + 30 * MB + 704 * KB);   // 20 KB

    // 0: weight transposes (tiny)
    wtrans_kernel<<<256,  128, 0, stream>>>(ws_q,    wsqT,  128, 256);
    wtrans_kernel<<<128,  256, 0, stream>>>(ws_o,    wsoT,  256, 128);
    wtrans_kernel<<<256,  128, 0, stream>>>(ww_q,    wwqT,  128, 256);
    wtrans_kernel<<<256,  128, 0, stream>>>(wc_q,    wcqT,  128, 256);
    wtrans_kernel<<<128,  256, 0, stream>>>(wc_o,    wcoT,  256, 128);
    wtrans_kernel<<<1280, 128, 0, stream>>>(w_split, wsplT, 128, 1280);

    // 1-2: featurize + embed
    embed_q_kernel  <<<NROW, 128, 0, stream>>>(xq, mq, w_q0, b_q0, w_q1, b_q1,
                                               w_cq, b_cq, w_qp, b_qp, qe, qe_bf);
    embed_obs_kernel<<<NROW, 128, 0, stream>>>(obs, mobs, w_o0, b_o0, w_o1, b_o1,
                                               w_cobs, b_cobs, w_kp, b_kp, oe, oe_bf);

    // 3: self-attn shared q=k=v projection (MFMA, per-head bf16)
    gemm_kernel<<<dim3(NROW/64, 4), 256, 0, stream>>>(oe_bf, wsqT, ws_qb, nullptr,
                                                      kvbs, 128, 256, 2, 0);
    // 4: self attention (MFMA flash)
    flash_attn_kernel<<<dim3(L_/64, NH_, B_), 256, 0, stream>>>(kvbs, kvbs, nullptr,
                                                                mobs, abuf);
    // 5: x = relu(oe + attn @ ws_o + ws_ob)   (MFMA, bf16 out)
    gemm_kernel<<<dim3(NROW/64, 2), 256, 0, stream>>>(abuf, wsoT, ws_ob, oe,
                                                      x_bf, 256, 128, 1, 1);

    // 6-10: mixing-weights path
    rowgemm_kernel<<<G_, 256, 0, stream>>>(mix_wt, ww_q, ww_qb, qmw);
    gemm_kernel<<<dim3(NROW/64, 4), 256, 0, stream>>>(x_bf, wwqT, ww_qb, nullptr,
                                                      kvf, 128, 256, 0, 0);
    attn_kernel<<<dim3((G_+3)/4, NH_, B_), 256, 0, stream>>>(qmw, kvf, nullptr, mobs,
                                                             mwat, G_, 0, G_ * 256);
    mwproj_kernel<<<B_ * G_, 128, 0, stream>>>(mwat, mix_wt, ww_o, ww_ob, mw_);
    mwfinal_kernel<<<B_, 64, 0, stream>>>(mw_, w_mix, b_mix,
                                          out + (size_t)B_ * G_ * L_ * H_);

    // 11-12: cross-attn projections (k==v share one projection)
    gemm_kernel<<<dim3(NROW/64, 4), 256, 0, stream>>>(qe_bf, wcqT, wc_qb, nullptr,
                                                      qcb, 128, 256, 2, 0);
    gemm_kernel<<<dim3(NROW/64, 4), 256, 0, stream>>>(x_bf, wcqT, wc_qb, nullptr,
                                                      kvcb, 128, 256, 2, 0);
    // 13: cross attention (MFMA flash)
    flash_attn_kernel<<<dim3(L_/64, NH_, B_), 256, 0, stream>>>(qcb, kvcb, mq,
                                                                mobs, abuf2);
    // 14: x2 = relu(qe + attn2 @ wc_o + wc_ob)
    gemm_kernel<<<dim3(NROW/64, 2), 256, 0, stream>>>(abuf2, wcoT, wc_ob, qe,
                                                      x2_bf, 256, 128, 1, 1);
    // 15: split + transpose store (MFMA)
    gemm_kernel<<<dim3(NROW/64, 20), 256, 0, stream>>>(x2_bf, wsplT, b_split, nullptr,
                                                       out, 128, 1280, 3, 0);

    (void)in_sizes; (void)n_in; (void)out_size;
}

// Round 5
// 561.589 us; speedup vs baseline: 6.6360x; 1.2060x over previous
//
#include <hip/hip_runtime.h>
#include <hip/hip_bf16.h>

#define B_  4
#define L_  2048      // LO == LQ == 2048
#define H_  128
#define NH_ 2
#define G_  10
#define NIN_ 41

typedef __hip_bfloat16 bf16;
typedef __attribute__((ext_vector_type(8))) short bf16x8s;  // 8 bf16 = 4 VGPRs
typedef __attribute__((ext_vector_type(4))) float f32x4;

__device__ __forceinline__ unsigned short f2bf_bits(float x) {
    __hip_bfloat16 h = __float2bfloat16(x);
    return *reinterpret_cast<unsigned short*>(&h);
}
__device__ __forceinline__ float us2f(unsigned short s) {
    return __uint_as_float(((unsigned int)s) << 16);
}

// ---------------------------------------------------------------------------
// K1: query featurize only -> (B*L, 256) bf16, masked
// ---------------------------------------------------------------------------
__global__ __launch_bounds__(128)
void featq_kernel(const float* __restrict__ xq, const float* __restrict__ mq,
                  const float* __restrict__ w_q0, const float* __restrict__ b_q0,
                  const float* __restrict__ w_q1, const float* __restrict__ b_q1,
                  const float* __restrict__ w_cq, const float* __restrict__ b_cq,
                  bf16* __restrict__ featq)
{
    const int row = blockIdx.x;
    const int j   = threadIdx.x;
    const float t   = xq[row * 2 + 0];
    const float chf = xq[row * 2 + 1];
    int ch = (int)chf; ch = max(0, min(NIN_ - 1, ch));
    const float m   = mq[row];
    float tf;
    if (j == 0) tf = t * w_q0[0] + b_q0[0];
    else        tf = __sinf(t * w_q1[j - 1] + b_q1[j - 1]);
    float cf = fmaxf(w_cq[ch * H_ + j] + b_cq[j], 0.f);
    featq[(size_t)row * 256 + j]       = __float2bfloat16(tf * m);
    featq[(size_t)row * 256 + 128 + j] = __float2bfloat16(cf * m);
}

// ---------------------------------------------------------------------------
// K2: obs featurize only -> (B*L, 288) bf16 (257 real, 31 zero pad), masked
// ---------------------------------------------------------------------------
__global__ __launch_bounds__(128)
void feato_kernel(const float* __restrict__ obs, const float* __restrict__ mobs,
                  const float* __restrict__ w_o0, const float* __restrict__ b_o0,
                  const float* __restrict__ w_o1, const float* __restrict__ b_o1,
                  const float* __restrict__ w_cobs, const float* __restrict__ b_cobs,
                  bf16* __restrict__ feato)
{
    const int row = blockIdx.x;
    const int j   = threadIdx.x;
    const float t   = obs[row * 3 + 0];
    const float chf = obs[row * 3 + 1];
    const float xv  = obs[row * 3 + 2];
    int ch = (int)chf; ch = max(0, min(NIN_ - 1, ch));
    const float m   = mobs[row];
    float tf;
    if (j == 0) tf = t * w_o0[0] + b_o0[0];
    else        tf = __sinf(t * w_o1[j - 1] + b_o1[j - 1]);
    float cf = fmaxf(w_cobs[ch * H_ + j] + b_cobs[j], 0.f);
    bf16* r = feato + (size_t)row * 288;
    r[j]       = __float2bfloat16(tf * m);
    r[128 + j] = __float2bfloat16(cf * m);
    if (j == 0) r[256] = __float2bfloat16(xv * m);
    if (j < 31) r[257 + j] = __float2bfloat16(0.f);
}

// ---------------------------------------------------------------------------
// All weight transposes (fp32 K x N -> bf16 N x Kp, zero pad k>=K) in 1 launch
// ---------------------------------------------------------------------------
struct WtArgs {
    const float* W[8];
    bf16* T[8];
    int K[8], Kp[8], N[8];
};
__global__ __launch_bounds__(288)
void wtrans_all_kernel(WtArgs a)
{
    const int i = blockIdx.y, n = blockIdx.x, k = threadIdx.x;
    if (n >= a.N[i] || k >= a.Kp[i]) return;
    a.T[i][(size_t)n * a.Kp[i] + k] =
        (k < a.K[i]) ? __float2bfloat16(a.W[i][(size_t)k * a.N[i] + n])
                     : __float2bfloat16(0.f);
}

// ---------------------------------------------------------------------------
// Generic MFMA GEMM: C = A(bf16 M x K) @ WT(bf16 N x K) + bias(fp32)
// optional bf16 residual R (M x N) added pre-ReLU. 64x64 tile, 4 waves.
// out modes: 0 fp32 row-major, 1 bf16 row-major, 2 bf16 per-head (B,NH,L,H),
//            3 fp32 split-transposed (B,G,L,H).
// ---------------------------------------------------------------------------
__global__ __launch_bounds__(256)
void gemm_kernel(const bf16* __restrict__ A, const bf16* __restrict__ WT,
                 const float* __restrict__ bias, const bf16* __restrict__ R,
                 void* __restrict__ out, int K, int N, int mode, int do_relu)
{
    const int wave = threadIdx.x >> 6, lane = threadIdx.x & 63;
    const int quad = lane >> 4, l15 = lane & 15;
    const int m0 = blockIdx.x * 64 + wave * 16;
    const int n0 = blockIdx.y * 64;

    f32x4 acc[4];
    #pragma unroll
    for (int c = 0; c < 4; c++) acc[c] = (f32x4){0.f, 0.f, 0.f, 0.f};

    const bf16* arow = A + (size_t)(m0 + l15) * K;
    #pragma unroll 4
    for (int kc = 0; kc < K; kc += 32) {
        bf16x8s af = *(const bf16x8s*)(arow + kc + quad * 8);
        #pragma unroll
        for (int c = 0; c < 4; c++) {
            bf16x8s wf = *(const bf16x8s*)(WT + (size_t)(n0 + c * 16 + l15) * K + kc + quad * 8);
            acc[c] = __builtin_amdgcn_mfma_f32_16x16x32_bf16(af, wf, acc[c], 0, 0, 0);
        }
    }

    #pragma unroll
    for (int c = 0; c < 4; c++) {
        const int n = n0 + c * 16 + l15;
        const float bv = bias[n];
        #pragma unroll
        for (int r = 0; r < 4; r++) {
            const int m = m0 + quad * 4 + r;
            float v = acc[c][r] + bv;
            if (R != nullptr) v += __bfloat162float(R[(size_t)m * N + n]);
            if (do_relu) v = fmaxf(v, 0.f);
            if (mode == 0) {
                ((float*)out)[(size_t)m * N + n] = v;
            } else if (mode == 1) {
                ((bf16*)out)[(size_t)m * N + n] = __float2bfloat16(v);
            } else if (mode == 2) {
                const int b = m >> 11, l = m & 2047, hh = n >> 7, d = n & 127;
                ((bf16*)out)[(((size_t)(b * NH_ + hh)) * L_ + l) * H_ + d] = __float2bfloat16(v);
            } else {
                const int b = m >> 11, q = m & 2047, g = n >> 7, hh = n & 127;
                ((float*)out)[(((size_t)(b * G_ + g)) * L_ + q) * H_ + hh] = v;
            }
        }
    }
}

// ---------------------------------------------------------------------------
// Flash attention v2: 512 threads = 8 waves = 2 q-subtiles x 4-way K-split.
// Q,KV bf16 (B,NH,L,H); O bf16 (B,L,NH*H). K==V. Grid (L/32, NH, B).
// In-block combine of the 4 K-split partials via LDS.
// ---------------------------------------------------------------------------
#define FRMS 136    // KVrm row stride (ushorts)
#define FTS  34     // KVT / Ps row stride (ushorts); word-stride 17 (odd)

__global__ __launch_bounds__(512, 4)
void flash_attn_kernel(const bf16* __restrict__ Qb, const bf16* __restrict__ KVb,
                       const float* __restrict__ mQ, const float* __restrict__ mK,
                       bf16* __restrict__ O)
{
    __shared__ __align__(16) char smem[78464];
    unsigned short* KVrm = (unsigned short*)smem;              // [kg][32][FRMS]
    unsigned short* KVT  = (unsigned short*)(smem + 34816);    // [kg][128][FTS]
    unsigned short* Ps   = (unsigned short*)(smem + 69632);    // [wave][16][FTS]
    float* qmv   = (float*)(smem + 78336);                     // 32
    float* Ocomb = (float*)smem;                               // [2][3][16][128]
    float* mcomb = (float*)(smem + 49152);                     // [2][3][16]
    float* lcomb = (float*)(smem + 49536);                     // [2][3][16]

    const int tid  = threadIdx.x;
    const int lane = tid & 63;
    const int wave = tid >> 6;
    const int kg   = wave >> 1;       // 0..3 key-split group
    const int qw   = wave & 1;        // 0..1 q-subtile
    const int quad = lane >> 4;
    const int l15  = lane & 15;
    const int h = blockIdx.y, b = blockIdx.z;
    const int q0 = blockIdx.x * 32;
    const int qbase = q0 + qw * 16;

    if (tid < 32) qmv[tid] = (mQ == nullptr) ? 1.f : mQ[b * L_ + q0 + tid];

    const bf16* qrow = Qb + (((size_t)(b * NH_ + h)) * L_ + qbase + l15) * H_;
    bf16x8s qf[4];
    #pragma unroll
    for (int kc = 0; kc < 4; kc++)
        qf[kc] = *(const bf16x8s*)(qrow + kc * 32 + quad * 8);

    float mo[4], li[4], qm[4];
    f32x4 Oacc[8];
    #pragma unroll
    for (int r = 0; r < 4; r++) { mo[r] = -1e30f; li[r] = 0.f; }
    #pragma unroll
    for (int c = 0; c < 8; c++) Oacc[c] = (f32x4){0.f, 0.f, 0.f, 0.f};
    __syncthreads();
    #pragma unroll
    for (int r = 0; r < 4; r++) qm[r] = qmv[qw * 16 + quad * 4 + r];

    const float SCALE = 0.08838834764831845f;    // 1/sqrt(128)
    const bf16* kvbase = KVb + (((size_t)(b * NH_ + h)) * L_) * H_;
    const float* mkb = mK + b * L_;
    unsigned short* KVrm_kg = KVrm + kg * 32 * FRMS;
    unsigned short* KVT_kg  = KVT  + kg * 128 * FTS;

    for (int it = 0; it < 16; it++) {
        const int kbase = kg * 512 + it * 32;
        __syncthreads();
        // ---- stage 32x128 KV tile (128 threads of kg-pair) ----
        {
            const int t  = qw * 64 + lane;     // 0..127
            const int d0 = (t & 15) * 8;
            const int pb = t >> 4;             // 0..7
            unsigned int* kt = (unsigned int*)KVT_kg;
            #pragma unroll
            for (int pi = 0; pi < 2; pi++) {
                const int pp = pb + pi * 8;    // key pair 0..15
                const bf16* src = kvbase + (size_t)(kbase + 2 * pp) * H_ + d0;
                uint4 va = *(const uint4*)(src);
                uint4 vb = *(const uint4*)(src + H_);
                *(uint4*)(&KVrm_kg[(2 * pp) * FRMS + d0])     = va;
                *(uint4*)(&KVrm_kg[(2 * pp + 1) * FRMS + d0]) = vb;
                const unsigned short* ka = (const unsigned short*)&va;
                const unsigned short* kb = (const unsigned short*)&vb;
                #pragma unroll
                for (int i = 0; i < 8; i++)
                    kt[(d0 + i) * (FTS / 2) + pp] =
                        (unsigned int)ka[i] | ((unsigned int)kb[i] << 16);
            }
        }
        __syncthreads();

        // ---- S = Q K^T ----
        f32x4 s0a = (f32x4){0.f,0.f,0.f,0.f}, s1a = (f32x4){0.f,0.f,0.f,0.f};
        #pragma unroll
        for (int kc = 0; kc < 4; kc++) {
            bf16x8s k0f = *(bf16x8s*)(&KVrm_kg[l15 * FRMS + kc * 32 + quad * 8]);
            bf16x8s k1f = *(bf16x8s*)(&KVrm_kg[(16 + l15) * FRMS + kc * 32 + quad * 8]);
            s0a = __builtin_amdgcn_mfma_f32_16x16x32_bf16(qf[kc], k0f, s0a, 0, 0, 0);
            s1a = __builtin_amdgcn_mfma_f32_16x16x32_bf16(qf[kc], k1f, s1a, 0, 0, 0);
        }

        const float km0 = mkb[kbase + l15];
        const float km1 = mkb[kbase + 16 + l15];
        float s0[4], s1[4], mx[4];
        #pragma unroll
        for (int r = 0; r < 4; r++) {
            s0[r] = (km0 != 0.f && qm[r] != 0.f) ? s0a[r] * SCALE : -1000000.f;
            s1[r] = (km1 != 0.f && qm[r] != 0.f) ? s1a[r] * SCALE : -1000000.f;
            mx[r] = fmaxf(s0[r], s1[r]);
        }
        #pragma unroll
        for (int off = 1; off < 16; off <<= 1)
            #pragma unroll
            for (int r = 0; r < 4; r++) mx[r] = fmaxf(mx[r], __shfl_xor(mx[r], off));

        float p0[4], p1[4], rs[4], al[4];
        #pragma unroll
        for (int r = 0; r < 4; r++) {
            const float mn = fmaxf(mo[r], mx[r]);
            al[r] = __expf(mo[r] - mn);
            mo[r] = mn;
            p0[r] = __expf(s0[r] - mn);
            p1[r] = __expf(s1[r] - mn);
            rs[r] = p0[r] + p1[r];
        }
        #pragma unroll
        for (int off = 1; off < 16; off <<= 1)
            #pragma unroll
            for (int r = 0; r < 4; r++) rs[r] += __shfl_xor(rs[r], off);
        #pragma unroll
        for (int r = 0; r < 4; r++) li[r] = li[r] * al[r] + rs[r];
        #pragma unroll
        for (int c = 0; c < 8; c++)
            #pragma unroll
            for (int r = 0; r < 4; r++) Oacc[c][r] *= al[r];

        unsigned short* pw = Ps + wave * 16 * FTS;
        #pragma unroll
        for (int r = 0; r < 4; r++) {
            pw[(quad * 4 + r) * FTS + l15]      = f2bf_bits(p0[r]);
            pw[(quad * 4 + r) * FTS + 16 + l15] = f2bf_bits(p1[r]);
        }
        bf16x8s pf = *(bf16x8s*)(&Ps[wave * 16 * FTS + l15 * FTS + quad * 8]);
        #pragma unroll
        for (int c = 0; c < 8; c++) {
            bf16x8s vf = *(bf16x8s*)(&KVT_kg[(c * 16 + l15) * FTS + quad * 8]);
            Oacc[c] = __builtin_amdgcn_mfma_f32_16x16x32_bf16(pf, vf, Oacc[c], 0, 0, 0);
        }
    }

    // ---- in-block combine of the 4 K-split partials ----
    __syncthreads();                    // everyone done reading KVT/Ps
    if (kg > 0) {
        const int s = kg - 1;
        float* oc = Ocomb + (size_t)((qw * 3 + s) * 16) * 128;
        #pragma unroll
        for (int c = 0; c < 8; c++)
            #pragma unroll
            for (int r = 0; r < 4; r++)
                oc[(quad * 4 + r) * 128 + c * 16 + l15] = Oacc[c][r];
        if (l15 == 0) {
            #pragma unroll
            for (int r = 0; r < 4; r++) {
                mcomb[(qw * 3 + s) * 16 + quad * 4 + r] = mo[r];
                lcomb[(qw * 3 + s) * 16 + quad * 4 + r] = li[r];
            }
        }
    }
    __syncthreads();
    if (kg == 0) {
        float ms[3][4], ls[3][4], M[4];
        #pragma unroll
        for (int r = 0; r < 4; r++) M[r] = mo[r];
        #pragma unroll
        for (int s = 0; s < 3; s++)
            #pragma unroll
            for (int r = 0; r < 4; r++) {
                ms[s][r] = mcomb[(qw * 3 + s) * 16 + quad * 4 + r];
                ls[s][r] = lcomb[(qw * 3 + s) * 16 + quad * 4 + r];
                M[r] = fmaxf(M[r], ms[s][r]);
            }
        float a0[4];
        #pragma unroll
        for (int r = 0; r < 4; r++) {
            a0[r] = __expf(mo[r] - M[r]);
            li[r] *= a0[r];
        }
        #pragma unroll
        for (int c = 0; c < 8; c++)
            #pragma unroll
            for (int r = 0; r < 4; r++) Oacc[c][r] *= a0[r];
        #pragma unroll
        for (int s = 0; s < 3; s++) {
            float as[4];
            #pragma unroll
            for (int r = 0; r < 4; r++) {
                as[r] = __expf(ms[s][r] - M[r]);
                li[r] += as[r] * ls[s][r];
            }
            const float* oc = Ocomb + (size_t)((qw * 3 + s) * 16) * 128;
            #pragma unroll
            for (int c = 0; c < 8; c++)
                #pragma unroll
                for (int r = 0; r < 4; r++)
                    Oacc[c][r] += as[r] * oc[(quad * 4 + r) * 128 + c * 16 + l15];
        }
        bf16* orow = O + ((size_t)b * L_ + qbase) * (NH_ * H_) + h * H_;
        #pragma unroll
        for (int r = 0; r < 4; r++) {
            const float inv = 1.f / li[r];
            #pragma unroll
            for (int c = 0; c < 8; c++)
                orow[(size_t)(quad * 4 + r) * (NH_ * H_) + c * 16 + l15] =
                    __float2bfloat16(Oacc[c][r] * inv);
        }
    }
}

// ---------------------------------------------------------------------------
// qmw builder: mix_wt(10x128) @ ww_q(128x256) + b -> bf16 per-head (2,16,128)
// ---------------------------------------------------------------------------
__global__ __launch_bounds__(256)
void qmwb_kernel(const float* __restrict__ mixwt, const float* __restrict__ W,
                 const float* __restrict__ bias, bf16* __restrict__ qmwb)
{
    const int g = blockIdx.x;          // 0..15
    const int c = threadIdx.x;         // 0..255
    const int h = c >> 7, d = c & 127;
    if (g >= G_) { qmwb[((size_t)h * 16 + g) * 128 + d] = __float2bfloat16(0.f); return; }
    __shared__ float xr[128];
    if (c < 128) xr[c] = mixwt[g * 128 + c];
    __syncthreads();
    float acc = bias[c];
    #pragma unroll 8
    for (int i = 0; i < 128; i++)
        acc += xr[i] * W[i * 256 + c];
    qmwb[((size_t)h * 16 + g) * 128 + d] = __float2bfloat16(acc);
}

// ---------------------------------------------------------------------------
// mw partial attention: 16-way K-split. grid (16, NH, B), 256 threads.
// Q: qmwb bf16 (NH,16,128) (10 valid). KV: kvmw bf16 (B,NH,L,H).
// writes unnormalized O partials + (m,l) stats.
// ---------------------------------------------------------------------------
__global__ __launch_bounds__(256)
void mwpartial_kernel(const bf16* __restrict__ qmwb, const bf16* __restrict__ kvmw,
                      const float* __restrict__ mK,
                      float* __restrict__ mwO, float* __restrict__ mwM,
                      float* __restrict__ mwL)
{
    __shared__ __align__(16) unsigned short Ks[128 * 136];
    __shared__ float Qs[10 * 128];
    __shared__ float sc[10 * 128];
    __shared__ float mst[10], lst[10];

    const int tid = threadIdx.x;
    const int split = blockIdx.x, h = blockIdx.y, b = blockIdx.z;
    const int kbase = split * 128;
    const float SCALE = 0.08838834764831845f;

    for (int idx = tid; idx < 1280; idx += 256)
        Qs[idx] = __bfloat162float(qmwb[((size_t)h * 16 + (idx >> 7)) * 128 + (idx & 127)]);
    {
        const int rr = tid >> 1, half = tid & 1;
        const bf16* src = kvmw + (((size_t)(b * NH_ + h)) * L_ + kbase + rr) * H_ + half * 64;
        #pragma unroll
        for (int i = 0; i < 8; i++)
            *(uint4*)(&Ks[rr * 136 + half * 64 + i * 8]) = *(const uint4*)(src + i * 8);
    }
    __syncthreads();

    // scores
    {
        const int j = tid & 127, qh = tid >> 7;
        float acc[5] = {0.f, 0.f, 0.f, 0.f, 0.f};
        for (int dc = 0; dc < 128; dc += 8) {
            bf16x8s kv = *(bf16x8s*)(&Ks[j * 136 + dc]);
            float kf[8];
            #pragma unroll
            for (int e = 0; e < 8; e++) kf[e] = us2f(((unsigned short*)&kv)[e]);
            #pragma unroll
            for (int qq = 0; qq < 5; qq++) {
                const float* Qrow = &Qs[(qh * 5 + qq) * 128 + dc];
                #pragma unroll
                for (int e = 0; e < 8; e++) acc[qq] += Qrow[e] * kf[e];
            }
        }
        const bool kz = (mK[b * L_ + kbase + j] == 0.f);
        #pragma unroll
        for (int qq = 0; qq < 5; qq++)
            sc[(qh * 5 + qq) * 128 + j] = kz ? -1000000.f : acc[qq] * SCALE;
    }
    __syncthreads();
    if (tid < 160) {
        const int q = tid >> 4, t16 = tid & 15;
        float m = -3.4e38f;
        for (int jj = t16; jj < 128; jj += 16) m = fmaxf(m, sc[q * 128 + jj]);
        #pragma unroll
        for (int off = 1; off < 16; off <<= 1) m = fmaxf(m, __shfl_xor(m, off));
        if (t16 == 0) mst[q] = m;
    }
    __syncthreads();
    {
        const int j = tid & 127, qh = tid >> 7;
        #pragma unroll
        for (int qq = 0; qq < 5; qq++) {
            const int idx = (qh * 5 + qq) * 128 + j;
            sc[idx] = __expf(sc[idx] - mst[qh * 5 + qq]);
        }
    }
    __syncthreads();
    if (tid < 160) {
        const int q = tid >> 4, t16 = tid & 15;
        float s = 0.f;
        for (int jj = t16; jj < 128; jj += 16) s += sc[q * 128 + jj];
        #pragma unroll
        for (int off = 1; off < 16; off <<= 1) s += __shfl_xor(s, off);
        if (t16 == 0) lst[q] = s;
    }
    __syncthreads();
    {
        const int d = tid & 127, qh = tid >> 7;
        float acc[5] = {0.f, 0.f, 0.f, 0.f, 0.f};
        for (int jj = 0; jj < 128; jj++) {
            const float v = us2f(Ks[jj * 136 + d]);
            #pragma unroll
            for (int qq = 0; qq < 5; qq++)
                acc[qq] += sc[(qh * 5 + qq) * 128 + jj] * v;
        }
        const size_t base = ((size_t)(b * NH_ + h) * 16 + split) * 10;
        #pragma unroll
        for (int qq = 0; qq < 5; qq++)
            mwO[(base + qh * 5 + qq) * 128 + d] = acc[qq];
    }
    if (tid < 10) {
        const size_t base = ((size_t)(b * NH_ + h) * 16 + split) * 10;
        mwM[base + tid] = mst[tid];
        mwL[base + tid] = lst[tid];
    }
}

// mw combine: merge 16 K-splits -> mwat (B*10, 256) fp32. grid 40 x 256
__global__ __launch_bounds__(256)
void mwcombine_kernel(const float* __restrict__ mwO, const float* __restrict__ mwM,
                      const float* __restrict__ mwL, float* __restrict__ mwat)
{
    const int bg = blockIdx.x;         // b*10+q
    const int b = bg / G_, q = bg % G_;
    const int h = threadIdx.x >> 7, d = threadIdx.x & 127;
    const size_t hb = (size_t)(b * NH_ + h) * 16;
    float M = -3.4e38f;
    for (int s = 0; s < 16; s++) M = fmaxf(M, mwM[(hb + s) * 10 + q]);
    float l = 0.f, o = 0.f;
    for (int s = 0; s < 16; s++) {
        const float a = __expf(mwM[(hb + s) * 10 + q] - M);
        l += a * mwL[(hb + s) * 10 + q];
        o += a * mwO[((hb + s) * 10 + q) * 128 + d];
    }
    mwat[(size_t)bg * 256 + h * 128 + d] = o / l;
}

// mw output projection: mw_ = mix_wt[g] + attn@ww_o + ww_ob ; grid B*G x 128
__global__ __launch_bounds__(128)
void mwproj_kernel(const float* __restrict__ A, const float* __restrict__ mixwt,
                   const float* __restrict__ W, const float* __restrict__ bias,
                   float* __restrict__ Y)
{
    const int bg  = blockIdx.x;
    const int g   = bg % G_;
    const int tid = threadIdx.x;
    __shared__ float ar[256];
    ar[tid]       = A[(size_t)bg * 256 + tid];
    ar[tid + 128] = A[(size_t)bg * 256 + tid + 128];
    __syncthreads();
    float acc = mixwt[g * 128 + tid] + bias[tid];
    #pragma unroll 8
    for (int i = 0; i < 256; i++)
        acc += ar[i] * W[i * 128 + tid];
    Y[(size_t)bg * 128 + tid] = acc;
}

__global__ __launch_bounds__(64)
void mwfinal_kernel(const float* __restrict__ MW, const float* __restrict__ wmix,
                    const float* __restrict__ bmix, float* __restrict__ out)
{
    const int b = blockIdx.x;
    const int g = threadIdx.x;
    __shared__ float z[16];
    if (g < G_) {
        float acc = bmix[0];
        for (int i = 0; i < 128; i++)
            acc += MW[((size_t)b * G_ + g) * 128 + i] * wmix[i];
        z[g] = acc;
    }
    __syncthreads();
    if (g == 0) {
        float mx = -3.4e38f;
        for (int i = 0; i < G_; i++) mx = fmaxf(mx, z[i]);
        float e[G_]; float s = 0.f;
        for (int i = 0; i < G_; i++) { e[i] = __expf(z[i] - mx); s += e[i]; }
        for (int i = 0; i < G_; i++) out[b * G_ + i] = e[i] / s;
    }
}

// ---------------------------------------------------------------------------
extern "C" void kernel_launch(void* const* d_in, const int* in_sizes, int n_in,
                              void* d_out, int out_size, void* d_ws, size_t ws_size,
                              hipStream_t stream)
{
    const float* obs    = (const float*)d_in[0];
    const float* mobs   = (const float*)d_in[1];
    const float* xq     = (const float*)d_in[2];
    const float* mq     = (const float*)d_in[3];
    const float* w_q0   = (const float*)d_in[4];
    const float* b_q0   = (const float*)d_in[5];
    const float* w_q1   = (const float*)d_in[6];
    const float* b_q1   = (const float*)d_in[7];
    const float* w_o0   = (const float*)d_in[8];
    const float* b_o0   = (const float*)d_in[9];
    const float* w_o1   = (const float*)d_in[10];
    const float* b_o1   = (const float*)d_in[11];
    const float* w_cobs = (const float*)d_in[12];
    const float* b_cobs = (const float*)d_in[13];
    const float* w_cq   = (const float*)d_in[14];
    const float* b_cq   = (const float*)d_in[15];
    const float* w_qp   = (const float*)d_in[16];
    const float* b_qp   = (const float*)d_in[17];
    const float* w_kp   = (const float*)d_in[18];
    const float* b_kp   = (const float*)d_in[19];
    const float* ws_q   = (const float*)d_in[20];
    const float* ws_qb  = (const float*)d_in[21];
    const float* ws_o   = (const float*)d_in[22];
    const float* ws_ob  = (const float*)d_in[23];
    const float* ww_q   = (const float*)d_in[24];
    const float* ww_qb  = (const float*)d_in[25];
    const float* ww_o   = (const float*)d_in[26];
    const float* ww_ob  = (const float*)d_in[27];
    const float* wc_q   = (const float*)d_in[28];
    const float* wc_qb  = (const float*)d_in[29];
    const float* wc_o   = (const float*)d_in[30];
    const float* wc_ob  = (const float*)d_in[31];
    const float* w_split= (const float*)d_in[32];
    const float* b_split= (const float*)d_in[33];
    const float* mix_wt = (const float*)d_in[34];
    const float* w_mix  = (const float*)d_in[35];
    const float* b_mix  = (const float*)d_in[36];

    float* out = (float*)d_out;
    char* ws  = (char*)d_ws;

    const size_t MB = (size_t)1 << 20;
    const size_t KB = (size_t)1 << 10;
    if (ws_size < 27 * MB) return;

    const int NROW = B_ * L_;          // 8192
    bf16* featq = (bf16*)(ws + 0);                 // 4 MB  -> kvbs -> qcb
    bf16* feato = (bf16*)(ws + 4 * MB);            // 4.5 MB -> kvcb
    bf16* qe_bf = (bf16*)(ws + 8 * MB + 512 * KB); // 2 MB
    bf16* oe_bf = (bf16*)(ws + 10 * MB + 512 * KB);// 2 MB
    bf16* abuf  = (bf16*)(ws + 12 * MB + 512 * KB);// 4 MB -> abuf2
    bf16* x_bf  = (bf16*)(ws + 16 * MB + 512 * KB);// 2 MB
    bf16* x2_bf = (bf16*)(ws + 18 * MB + 512 * KB);// 2 MB
    bf16* kvmw  = (bf16*)(ws + 20 * MB + 512 * KB);// 4 MB
    char* wbase = ws + 24 * MB + 512 * KB;
    bf16* wqpT  = (bf16*)(wbase + 0);              // 64 KB (128 x 256)
    bf16* wkpT  = (bf16*)(wbase + 64 * KB);        // 72 KB (128 x 288)
    bf16* wsqT  = (bf16*)(wbase + 136 * KB);       // 64 KB (256 x 128)
    bf16* wsoT  = (bf16*)(wbase + 200 * KB);       // 64 KB (128 x 256)
    bf16* wwqT  = (bf16*)(wbase + 264 * KB);       // 64 KB
    bf16* wcqT  = (bf16*)(wbase + 328 * KB);       // 64 KB
    bf16* wcoT  = (bf16*)(wbase + 392 * KB);       // 64 KB
    bf16* wsplT = (bf16*)(wbase + 456 * KB);       // 320 KB (1280 x 128)
    bf16* qmwb  = (bf16*)(wbase + 776 * KB);       // 8 KB (2,16,128)
    float* mwO  = (float*)(wbase + 784 * KB);      // 640 KB
    float* mwM  = (float*)(wbase + 1424 * KB);     // 5 KB
    float* mwL  = (float*)(wbase + 1432 * KB);     // 5 KB
    float* mwat = (float*)(wbase + 1440 * KB);     // 40 KB
    float* mw_  = (float*)(wbase + 1480 * KB);     // 20 KB
    bf16* kvbs  = featq;
    bf16* qcb   = featq;
    bf16* kvcb  = feato;
    bf16* abuf2 = abuf;

    // 0: all weight transposes in one launch
    WtArgs wa;
    wa.W[0]=w_qp;   wa.T[0]=wqpT;  wa.K[0]=256; wa.Kp[0]=256; wa.N[0]=128;
    wa.W[1]=w_kp;   wa.T[1]=wkpT;  wa.K[1]=257; wa.Kp[1]=288; wa.N[1]=128;
    wa.W[2]=ws_q;   wa.T[2]=wsqT;  wa.K[2]=128; wa.Kp[2]=128; wa.N[2]=256;
    wa.W[3]=ws_o;   wa.T[3]=wsoT;  wa.K[3]=256; wa.Kp[3]=256; wa.N[3]=128;
    wa.W[4]=ww_q;   wa.T[4]=wwqT;  wa.K[4]=128; wa.Kp[4]=128; wa.N[4]=256;
    wa.W[5]=wc_q;   wa.T[5]=wcqT;  wa.K[5]=128; wa.Kp[5]=128; wa.N[5]=256;
    wa.W[6]=wc_o;   wa.T[6]=wcoT;  wa.K[6]=256; wa.Kp[6]=256; wa.N[6]=128;
    wa.W[7]=w_split;wa.T[7]=wsplT; wa.K[7]=128; wa.Kp[7]=128; wa.N[7]=1280;
    wtrans_all_kernel<<<dim3(1280, 8), 288, 0, stream>>>(wa);

    // 1-2: featurize
    featq_kernel<<<NROW, 128, 0, stream>>>(xq, mq, w_q0, b_q0, w_q1, b_q1,
                                           w_cq, b_cq, featq);
    feato_kernel<<<NROW, 128, 0, stream>>>(obs, mobs, w_o0, b_o0, w_o1, b_o1,
                                           w_cobs, b_cobs, feato);
    // 3-4: embed projections (MFMA)
    gemm_kernel<<<dim3(NROW/64, 2), 256, 0, stream>>>(featq, wqpT, b_qp, nullptr,
                                                      qe_bf, 256, 128, 1, 0);
    gemm_kernel<<<dim3(NROW/64, 2), 256, 0, stream>>>(feato, wkpT, b_kp, nullptr,
                                                      oe_bf, 288, 128, 1, 0);
    // 5: self-attn shared q=k=v projection (per-head bf16)
    gemm_kernel<<<dim3(NROW/64, 4), 256, 0, stream>>>(oe_bf, wsqT, ws_qb, nullptr,
                                                      kvbs, 128, 256, 2, 0);
    // 6: self attention
    flash_attn_kernel<<<dim3(L_/32, NH_, B_), 512, 0, stream>>>(kvbs, kvbs, nullptr,
                                                                mobs, abuf);
    // 7: x = relu(oe + attn @ ws_o + ws_ob)
    gemm_kernel<<<dim3(NROW/64, 2), 256, 0, stream>>>(abuf, wsoT, ws_ob, oe_bf,
                                                      x_bf, 256, 128, 1, 1);
    // 8-13: mixing-weights path
    qmwb_kernel<<<16, 256, 0, stream>>>(mix_wt, ww_q, ww_qb, qmwb);
    gemm_kernel<<<dim3(NROW/64, 4), 256, 0, stream>>>(x_bf, wwqT, ww_qb, nullptr,
                                                      kvmw, 128, 256, 2, 0);
    mwpartial_kernel<<<dim3(16, NH_, B_), 256, 0, stream>>>(qmwb, kvmw, mobs,
                                                            mwO, mwM, mwL);
    mwcombine_kernel<<<B_ * G_, 256, 0, stream>>>(mwO, mwM, mwL, mwat);
    mwproj_kernel<<<B_ * G_, 128, 0, stream>>>(mwat, mix_wt, ww_o, ww_ob, mw_);
    mwfinal_kernel<<<B_, 64, 0, stream>>>(mw_, w_mix, b_mix,
                                          out + (size_t)B_ * G_ * L_ * H_);
    // 14-15: cross-attn projections (k==v share one projection)
    gemm_kernel<<<dim3(NROW/64, 4), 256, 0, stream>>>(qe_bf, wcqT, wc_qb, nullptr,
                                                      qcb, 128, 256, 2, 0);
    gemm_kernel<<<dim3(NROW/64, 4), 256, 0, stream>>>(x_bf, wcqT, wc_qb, nullptr,
                                                      kvcb, 128, 256, 2, 0);
    // 16: cross attention
    flash_attn_kernel<<<dim3(L_/32, NH_, B_), 512, 0, stream>>>(qcb, kvcb, mq,
                                                                mobs, abuf2);
    // 17: x2 = relu(qe + attn2 @ wc_o + wc_ob)
    gemm_kernel<<<dim3(NROW/64, 2), 256, 0, stream>>>(abuf2, wcoT, wc_ob, qe_bf,
                                                      x2_bf, 256, 128, 1, 1);
    // 18: split + transpose store (MFMA)
    gemm_kernel<<<dim3(NROW/64, 20), 256, 0, stream>>>(x2_bf, wsplT, b_split, nullptr,
                                                       out, 128, 1280, 3, 0);

    (void)in_sizes; (void)n_in; (void)out_size;
}

// Round 6
// 559.098 us; speedup vs baseline: 6.6656x; 1.0045x over previous
//
#include <hip/hip_runtime.h>
#include <hip/hip_bf16.h>

#define B_  4
#define L_  2048      // LO == LQ == 2048
#define H_  128
#define NH_ 2
#define G_  10
#define NIN_ 41

typedef __hip_bfloat16 bf16;
typedef __attribute__((ext_vector_type(8))) short bf16x8s;  // 8 bf16 = 4 VGPRs
typedef __attribute__((ext_vector_type(4))) float f32x4;

__device__ __forceinline__ unsigned short f2bf_bits(float x) {
    __hip_bfloat16 h = __float2bfloat16(x);
    return *reinterpret_cast<unsigned short*>(&h);
}
__device__ __forceinline__ float us2f(unsigned short s) {
    return __uint_as_float(((unsigned int)s) << 16);
}

// ---------------------------------------------------------------------------
// K1: query featurize only -> (B*L, 256) bf16, masked
// ---------------------------------------------------------------------------
__global__ __launch_bounds__(128)
void featq_kernel(const float* __restrict__ xq, const float* __restrict__ mq,
                  const float* __restrict__ w_q0, const float* __restrict__ b_q0,
                  const float* __restrict__ w_q1, const float* __restrict__ b_q1,
                  const float* __restrict__ w_cq, const float* __restrict__ b_cq,
                  bf16* __restrict__ featq)
{
    const int row = blockIdx.x;
    const int j   = threadIdx.x;
    const float t   = xq[row * 2 + 0];
    const float chf = xq[row * 2 + 1];
    int ch = (int)chf; ch = max(0, min(NIN_ - 1, ch));
    const float m   = mq[row];
    float tf;
    if (j == 0) tf = t * w_q0[0] + b_q0[0];
    else        tf = __sinf(t * w_q1[j - 1] + b_q1[j - 1]);
    float cf = fmaxf(w_cq[ch * H_ + j] + b_cq[j], 0.f);
    featq[(size_t)row * 256 + j]       = __float2bfloat16(tf * m);
    featq[(size_t)row * 256 + 128 + j] = __float2bfloat16(cf * m);
}

// ---------------------------------------------------------------------------
// K2: obs featurize only -> (B*L, 288) bf16 (257 real, 31 zero pad), masked
// ---------------------------------------------------------------------------
__global__ __launch_bounds__(128)
void feato_kernel(const float* __restrict__ obs, const float* __restrict__ mobs,
                  const float* __restrict__ w_o0, const float* __restrict__ b_o0,
                  const float* __restrict__ w_o1, const float* __restrict__ b_o1,
                  const float* __restrict__ w_cobs, const float* __restrict__ b_cobs,
                  bf16* __restrict__ feato)
{
    const int row = blockIdx.x;
    const int j   = threadIdx.x;
    const float t   = obs[row * 3 + 0];
    const float chf = obs[row * 3 + 1];
    const float xv  = obs[row * 3 + 2];
    int ch = (int)chf; ch = max(0, min(NIN_ - 1, ch));
    const float m   = mobs[row];
    float tf;
    if (j == 0) tf = t * w_o0[0] + b_o0[0];
    else        tf = __sinf(t * w_o1[j - 1] + b_o1[j - 1]);
    float cf = fmaxf(w_cobs[ch * H_ + j] + b_cobs[j], 0.f);
    bf16* r = feato + (size_t)row * 288;
    r[j]       = __float2bfloat16(tf * m);
    r[128 + j] = __float2bfloat16(cf * m);
    if (j == 0) r[256] = __float2bfloat16(xv * m);
    if (j < 31) r[257 + j] = __float2bfloat16(0.f);
}

// ---------------------------------------------------------------------------
// All weight transposes (fp32 K x N -> bf16 N x Kp, zero pad k>=K) in 1 launch
// ---------------------------------------------------------------------------
struct WtArgs {
    const float* W[8];
    bf16* T[8];
    int K[8], Kp[8], N[8];
};
__global__ __launch_bounds__(288)
void wtrans_all_kernel(WtArgs a)
{
    const int i = blockIdx.y, n = blockIdx.x, k = threadIdx.x;
    if (n >= a.N[i] || k >= a.Kp[i]) return;
    a.T[i][(size_t)n * a.Kp[i] + k] =
        (k < a.K[i]) ? __float2bfloat16(a.W[i][(size_t)k * a.N[i] + n])
                     : __float2bfloat16(0.f);
}

// ---------------------------------------------------------------------------
// KV transpose: in (BH, L, H) -> out (BH, H, L). grid (L/64, BH), 256 thr.
// ---------------------------------------------------------------------------
__global__ __launch_bounds__(256)
void kvtrans_kernel(const bf16* __restrict__ in, bf16* __restrict__ out)
{
    __shared__ unsigned short tile[64 * 136];
    const int tid = threadIdx.x;
    const int l0 = blockIdx.x * 64;
    const int bh = blockIdx.y;
    const unsigned short* src = (const unsigned short*)(in + (size_t)bh * L_ * H_);
    unsigned short* dst = (unsigned short*)(out + (size_t)bh * H_ * L_);
    #pragma unroll
    for (int p = 0; p < 4; p++) {
        const int l = p * 16 + (tid >> 4);
        const int d0 = (tid & 15) * 8;
        *(uint4*)&tile[l * 136 + d0] = *(const uint4*)&src[(size_t)(l0 + l) * H_ + d0];
    }
    __syncthreads();
    const int d  = tid >> 1;
    const int lh = (tid & 1) * 32;
    unsigned short buf[32];
    #pragma unroll
    for (int j = 0; j < 32; j++) buf[j] = tile[(lh + j) * 136 + d];
    #pragma unroll
    for (int j = 0; j < 4; j++)
        *(uint4*)&dst[(size_t)d * L_ + l0 + lh + j * 8] = *(uint4*)&buf[j * 8];
}

// ---------------------------------------------------------------------------
// Generic MFMA GEMM: C = A(bf16 M x K) @ WT(bf16 N x K) + bias(fp32)
// optional bf16 residual R (M x N) added pre-ReLU. 64x64 tile, 4 waves.
// out modes: 0 fp32 row-major, 1 bf16 row-major, 2 bf16 per-head (B,NH,L,H),
//            3 fp32 split-transposed (B,G,L,H).
// ---------------------------------------------------------------------------
__global__ __launch_bounds__(256)
void gemm_kernel(const bf16* __restrict__ A, const bf16* __restrict__ WT,
                 const float* __restrict__ bias, const bf16* __restrict__ R,
                 void* __restrict__ out, int K, int N, int mode, int do_relu)
{
    const int wave = threadIdx.x >> 6, lane = threadIdx.x & 63;
    const int quad = lane >> 4, l15 = lane & 15;
    const int m0 = blockIdx.x * 64 + wave * 16;
    const int n0 = blockIdx.y * 64;

    f32x4 acc[4];
    #pragma unroll
    for (int c = 0; c < 4; c++) acc[c] = (f32x4){0.f, 0.f, 0.f, 0.f};

    const bf16* arow = A + (size_t)(m0 + l15) * K;
    #pragma unroll 4
    for (int kc = 0; kc < K; kc += 32) {
        bf16x8s af = *(const bf16x8s*)(arow + kc + quad * 8);
        #pragma unroll
        for (int c = 0; c < 4; c++) {
            bf16x8s wf = *(const bf16x8s*)(WT + (size_t)(n0 + c * 16 + l15) * K + kc + quad * 8);
            acc[c] = __builtin_amdgcn_mfma_f32_16x16x32_bf16(af, wf, acc[c], 0, 0, 0);
        }
    }

    #pragma unroll
    for (int c = 0; c < 4; c++) {
        const int n = n0 + c * 16 + l15;
        const float bv = bias[n];
        #pragma unroll
        for (int r = 0; r < 4; r++) {
            const int m = m0 + quad * 4 + r;
            float v = acc[c][r] + bv;
            if (R != nullptr) v += __bfloat162float(R[(size_t)m * N + n]);
            if (do_relu) v = fmaxf(v, 0.f);
            if (mode == 0) {
                ((float*)out)[(size_t)m * N + n] = v;
            } else if (mode == 1) {
                ((bf16*)out)[(size_t)m * N + n] = __float2bfloat16(v);
            } else if (mode == 2) {
                const int b = m >> 11, l = m & 2047, hh = n >> 7, d = n & 127;
                ((bf16*)out)[(((size_t)(b * NH_ + hh)) * L_ + l) * H_ + d] = __float2bfloat16(v);
            } else {
                const int b = m >> 11, q = m & 2047, g = n >> 7, hh = n & 127;
                ((float*)out)[(((size_t)(b * G_ + g)) * L_ + q) * H_ + hh] = v;
            }
        }
    }
}

// ---------------------------------------------------------------------------
// Flash attention v3: barrier-free inner loop, all operands from global (L2).
// Q,KV bf16 (BH,L,H); KVT bf16 (BH,H,L); O bf16 (B,L,NH*H). K==V.
// Block: 512 thr = 8 waves = 4 q-subtiles(16q) x 2-way K-split.
// Grid: (BH, L/64) -- bh fastest => one (b,h) per XCD (KV L2-resident).
// ---------------------------------------------------------------------------
#define FTS 40      // Ps row stride (ushorts): 80 B, 16 B-aligned b128 reads

__global__ __launch_bounds__(512, 2)
void flash_attn_kernel(const bf16* __restrict__ Qb, const bf16* __restrict__ KVb,
                       const bf16* __restrict__ KVTb,
                       const float* __restrict__ mQ, const float* __restrict__ mK,
                       bf16* __restrict__ O)
{
    __shared__ __align__(16) char smem[34304];
    float* kmrow = (float*)smem;                         // 8 KB (loop phase)
    float* qmv   = (float*)(smem + 8192);                // 256 B
    unsigned short* Ps = (unsigned short*)(smem + 8448); // 8*16*40*2 = 10240 B
    float* Ocomb = (float*)smem;                         // 4*16*132*4 = 33792 B (combine)
    float* mcomb = (float*)(smem + 33792);               // 256 B
    float* lcomb = (float*)(smem + 34048);               // 256 B

    const int tid  = threadIdx.x;
    const int lane = tid & 63;
    const int wave = tid >> 6;
    const int qsub = wave & 3;        // 4 q-subtiles of 16
    const int ksid = wave >> 2;       // 2-way K split
    const int quad = lane >> 4;
    const int l15  = lane & 15;
    const int bh = blockIdx.x;        // b*NH + h
    const int b  = bh >> 1, h = bh & 1;
    const int q0 = blockIdx.y * 64;
    const int qbase = q0 + qsub * 16;

    for (int i = tid; i < L_; i += 512) kmrow[i] = mK[b * L_ + i];
    if (tid < 64) qmv[tid] = (mQ == nullptr) ? 1.f : mQ[b * L_ + q0 + tid];

    // Q fragments from global (row-major per-head)
    const bf16* qrow = Qb + ((size_t)bh * L_ + qbase + l15) * H_;
    bf16x8s qf[4];
    #pragma unroll
    for (int kc = 0; kc < 4; kc++)
        qf[kc] = *(const bf16x8s*)(qrow + kc * 32 + quad * 8);

    __syncthreads();
    float qm[4];
    #pragma unroll
    for (int r = 0; r < 4; r++) qm[r] = qmv[qsub * 16 + quad * 4 + r];

    float mo[4], li[4];
    f32x4 Oacc[8];
    #pragma unroll
    for (int r = 0; r < 4; r++) { mo[r] = -1e30f; li[r] = 0.f; }
    #pragma unroll
    for (int c = 0; c < 8; c++) Oacc[c] = (f32x4){0.f, 0.f, 0.f, 0.f};

    const float SCALE = 0.08838834764831845f;    // 1/sqrt(128)
    const bf16* kvb = KVb  + (size_t)bh * L_ * H_;
    const bf16* kvt = KVTb + (size_t)bh * H_ * L_;
    unsigned short* pw = Ps + wave * 16 * FTS;

    // K-frag double buffer (software pipeline)
    bf16x8s kf[2][8];
    {
        const int kb0 = ksid * 1024;
        #pragma unroll
        for (int kc = 0; kc < 4; kc++) {
            kf[0][kc]     = *(const bf16x8s*)(kvb + (size_t)(kb0 + l15) * H_ + kc * 32 + quad * 8);
            kf[0][4 + kc] = *(const bf16x8s*)(kvb + (size_t)(kb0 + 16 + l15) * H_ + kc * 32 + quad * 8);
        }
    }

    #pragma unroll 2
    for (int it = 0; it < 32; it++) {
        const int cur = it & 1;
        const int kbase = ksid * 1024 + it * 32;

        // ---- S = Q K^T ----
        f32x4 s0a = (f32x4){0.f,0.f,0.f,0.f}, s1a = (f32x4){0.f,0.f,0.f,0.f};
        #pragma unroll
        for (int kc = 0; kc < 4; kc++) {
            s0a = __builtin_amdgcn_mfma_f32_16x16x32_bf16(qf[kc], kf[cur][kc],     s0a, 0, 0, 0);
            s1a = __builtin_amdgcn_mfma_f32_16x16x32_bf16(qf[kc], kf[cur][4 + kc], s1a, 0, 0, 0);
        }

        // ---- V^T fragments for this tile (latency hides under softmax) ----
        bf16x8s vf[8];
        #pragma unroll
        for (int c = 0; c < 8; c++)
            vf[c] = *(const bf16x8s*)(kvt + (size_t)(c * 16 + l15) * L_ + kbase + quad * 8);

        // ---- prefetch next K tile ----
        if (it < 31) {
            const int kn = kbase + 32;
            #pragma unroll
            for (int kc = 0; kc < 4; kc++) {
                kf[cur ^ 1][kc]     = *(const bf16x8s*)(kvb + (size_t)(kn + l15) * H_ + kc * 32 + quad * 8);
                kf[cur ^ 1][4 + kc] = *(const bf16x8s*)(kvb + (size_t)(kn + 16 + l15) * H_ + kc * 32 + quad * 8);
            }
        }

        // ---- mask + online softmax ----
        const float km0 = kmrow[kbase + l15];
        const float km1 = kmrow[kbase + 16 + l15];
        float s0[4], s1[4], mx[4];
        #pragma unroll
        for (int r = 0; r < 4; r++) {
            s0[r] = (km0 != 0.f && qm[r] != 0.f) ? s0a[r] * SCALE : -1000000.f;
            s1[r] = (km1 != 0.f && qm[r] != 0.f) ? s1a[r] * SCALE : -1000000.f;
            mx[r] = fmaxf(s0[r], s1[r]);
        }
        #pragma unroll
        for (int off = 1; off < 16; off <<= 1)
            #pragma unroll
            for (int r = 0; r < 4; r++) mx[r] = fmaxf(mx[r], __shfl_xor(mx[r], off));

        float p0[4], p1[4], rs[4], al[4];
        #pragma unroll
        for (int r = 0; r < 4; r++) {
            const float mn = fmaxf(mo[r], mx[r]);
            al[r] = __expf(mo[r] - mn);
            mo[r] = mn;
            p0[r] = __expf(s0[r] - mn);
            p1[r] = __expf(s1[r] - mn);
            rs[r] = p0[r] + p1[r];
        }
        #pragma unroll
        for (int off = 1; off < 16; off <<= 1)
            #pragma unroll
            for (int r = 0; r < 4; r++) rs[r] += __shfl_xor(rs[r], off);
        #pragma unroll
        for (int r = 0; r < 4; r++) li[r] = li[r] * al[r] + rs[r];
        #pragma unroll
        for (int c = 0; c < 8; c++)
            #pragma unroll
            for (int r = 0; r < 4; r++) Oacc[c][r] *= al[r];

        // ---- P -> LDS (wave-private, no barrier) -> A-frag ----
        #pragma unroll
        for (int r = 0; r < 4; r++) {
            pw[(quad * 4 + r) * FTS + l15]      = f2bf_bits(p0[r]);
            pw[(quad * 4 + r) * FTS + 16 + l15] = f2bf_bits(p1[r]);
        }
        bf16x8s pf = *(bf16x8s*)(&pw[l15 * FTS + quad * 8]);

        // ---- O += P V ----
        #pragma unroll
        for (int c = 0; c < 8; c++)
            Oacc[c] = __builtin_amdgcn_mfma_f32_16x16x32_bf16(pf, vf[c], Oacc[c], 0, 0, 0);
    }

    // ---- 2-way K-split combine ----
    __syncthreads();
    if (ksid == 1) {
        float* oc = Ocomb + (size_t)(qsub * 16) * 132;
        #pragma unroll
        for (int c = 0; c < 8; c++)
            #pragma unroll
            for (int r = 0; r < 4; r++)
                oc[(size_t)(quad * 4 + r) * (4 * 16 * 132 / 64) * 0 + (quad * 4 + r) * 132 * 16 / 16] = 0.f; // placeholder removed below
    }
    // NOTE: real combine below (the above dead store optimized out; kept structure simple)
    if (ksid == 1) {
        #pragma unroll
        for (int c = 0; c < 8; c++)
            #pragma unroll
            for (int r = 0; r < 4; r++)
                Ocomb[(size_t)(qsub * 16 + quad * 4 + r) * 132 + c * 16 + l15] = Oacc[c][r];
        if (l15 == 0) {
            #pragma unroll
            for (int r = 0; r < 4; r++) {
                mcomb[qsub * 16 + quad * 4 + r] = mo[r];
                lcomb[qsub * 16 + quad * 4 + r] = li[r];
            }
        }
    }
    __syncthreads();
    if (ksid == 0) {
        float ms[4], ls[4], M[4], a0[4], as[4];
        #pragma unroll
        for (int r = 0; r < 4; r++) {
            ms[r] = mcomb[qsub * 16 + quad * 4 + r];
            ls[r] = lcomb[qsub * 16 + quad * 4 + r];
            M[r]  = fmaxf(mo[r], ms[r]);
            a0[r] = __expf(mo[r] - M[r]);
            as[r] = __expf(ms[r] - M[r]);
            li[r] = a0[r] * li[r] + as[r] * ls[r];
        }
        bf16* orow = O + ((size_t)b * L_ + qbase) * (NH_ * H_) + h * H_;
        #pragma unroll
        for (int r = 0; r < 4; r++) {
            const float inv = 1.f / li[r];
            #pragma unroll
            for (int c = 0; c < 8; c++) {
                const float v = a0[r] * Oacc[c][r] +
                    as[r] * Ocomb[(size_t)(qsub * 16 + quad * 4 + r) * 132 + c * 16 + l15];
                orow[(size_t)(quad * 4 + r) * (NH_ * H_) + c * 16 + l15] =
                    __float2bfloat16(v * inv);
            }
        }
    }
}

// ---------------------------------------------------------------------------
// qmw builder: mix_wt(10x128) @ ww_q(128x256) + b -> bf16 per-head (2,16,128)
// ---------------------------------------------------------------------------
__global__ __launch_bounds__(256)
void qmwb_kernel(const float* __restrict__ mixwt, const float* __restrict__ W,
                 const float* __restrict__ bias, bf16* __restrict__ qmwb)
{
    const int g = blockIdx.x;          // 0..15
    const int c = threadIdx.x;         // 0..255
    const int h = c >> 7, d = c & 127;
    if (g >= G_) { qmwb[((size_t)h * 16 + g) * 128 + d] = __float2bfloat16(0.f); return; }
    __shared__ float xr[128];
    if (c < 128) xr[c] = mixwt[g * 128 + c];
    __syncthreads();
    float acc = bias[c];
    #pragma unroll 8
    for (int i = 0; i < 128; i++)
        acc += xr[i] * W[i * 256 + c];
    qmwb[((size_t)h * 16 + g) * 128 + d] = __float2bfloat16(acc);
}

// ---------------------------------------------------------------------------
// mw partial attention: 16-way K-split. grid (16, NH, B), 256 threads.
// ---------------------------------------------------------------------------
__global__ __launch_bounds__(256)
void mwpartial_kernel(const bf16* __restrict__ qmwb, const bf16* __restrict__ kvmw,
                      const float* __restrict__ mK,
                      float* __restrict__ mwO, float* __restrict__ mwM,
                      float* __restrict__ mwL)
{
    __shared__ __align__(16) unsigned short Ks[128 * 136];
    __shared__ float Qs[10 * 128];
    __shared__ float sc[10 * 128];
    __shared__ float mst[10], lst[10];

    const int tid = threadIdx.x;
    const int split = blockIdx.x, h = blockIdx.y, b = blockIdx.z;
    const int kbase = split * 128;
    const float SCALE = 0.08838834764831845f;

    for (int idx = tid; idx < 1280; idx += 256)
        Qs[idx] = __bfloat162float(qmwb[((size_t)h * 16 + (idx >> 7)) * 128 + (idx & 127)]);
    {
        const int rr = tid >> 1, half = tid & 1;
        const bf16* src = kvmw + (((size_t)(b * NH_ + h)) * L_ + kbase + rr) * H_ + half * 64;
        #pragma unroll
        for (int i = 0; i < 8; i++)
            *(uint4*)(&Ks[rr * 136 + half * 64 + i * 8]) = *(const uint4*)(src + i * 8);
    }
    __syncthreads();

    {
        const int j = tid & 127, qh = tid >> 7;
        float acc[5] = {0.f, 0.f, 0.f, 0.f, 0.f};
        for (int dc = 0; dc < 128; dc += 8) {
            bf16x8s kv = *(bf16x8s*)(&Ks[j * 136 + dc]);
            float kf[8];
            #pragma unroll
            for (int e = 0; e < 8; e++) kf[e] = us2f(((unsigned short*)&kv)[e]);
            #pragma unroll
            for (int qq = 0; qq < 5; qq++) {
                const float* Qrow = &Qs[(qh * 5 + qq) * 128 + dc];
                #pragma unroll
                for (int e = 0; e < 8; e++) acc[qq] += Qrow[e] * kf[e];
            }
        }
        const bool kz = (mK[b * L_ + kbase + j] == 0.f);
        #pragma unroll
        for (int qq = 0; qq < 5; qq++)
            sc[(qh * 5 + qq) * 128 + j] = kz ? -1000000.f : acc[qq] * SCALE;
    }
    __syncthreads();
    if (tid < 160) {
        const int q = tid >> 4, t16 = tid & 15;
        float m = -3.4e38f;
        for (int jj = t16; jj < 128; jj += 16) m = fmaxf(m, sc[q * 128 + jj]);
        #pragma unroll
        for (int off = 1; off < 16; off <<= 1) m = fmaxf(m, __shfl_xor(m, off));
        if (t16 == 0) mst[q] = m;
    }
    __syncthreads();
    {
        const int j = tid & 127, qh = tid >> 7;
        #pragma unroll
        for (int qq = 0; qq < 5; qq++) {
            const int idx = (qh * 5 + qq) * 128 + j;
            sc[idx] = __expf(sc[idx] - mst[qh * 5 + qq]);
        }
    }
    __syncthreads();
    if (tid < 160) {
        const int q = tid >> 4, t16 = tid & 15;
        float s = 0.f;
        for (int jj = t16; jj < 128; jj += 16) s += sc[q * 128 + jj];
        #pragma unroll
        for (int off = 1; off < 16; off <<= 1) s += __shfl_xor(s, off);
        if (t16 == 0) lst[q] = s;
    }
    __syncthreads();
    {
        const int d = tid & 127, qh = tid >> 7;
        float acc[5] = {0.f, 0.f, 0.f, 0.f, 0.f};
        for (int jj = 0; jj < 128; jj++) {
            const float v = us2f(Ks[jj * 136 + d]);
            #pragma unroll
            for (int qq = 0; qq < 5; qq++)
                acc[qq] += sc[(qh * 5 + qq) * 128 + jj] * v;
        }
        const size_t base = ((size_t)(b * NH_ + h) * 16 + split) * 10;
        #pragma unroll
        for (int qq = 0; qq < 5; qq++)
            mwO[(base + qh * 5 + qq) * 128 + d] = acc[qq];
    }
    if (tid < 10) {
        const size_t base = ((size_t)(b * NH_ + h) * 16 + split) * 10;
        mwM[base + tid] = mst[tid];
        mwL[base + tid] = lst[tid];
    }
}

// mw combine: merge 16 K-splits -> mwat (B*10, 256) fp32. grid 40 x 256
__global__ __launch_bounds__(256)
void mwcombine_kernel(const float* __restrict__ mwO, const float* __restrict__ mwM,
                      const float* __restrict__ mwL, float* __restrict__ mwat)
{
    const int bg = blockIdx.x;
    const int b = bg / G_, q = bg % G_;
    const int h = threadIdx.x >> 7, d = threadIdx.x & 127;
    const size_t hb = (size_t)(b * NH_ + h) * 16;
    float M = -3.4e38f;
    for (int s = 0; s < 16; s++) M = fmaxf(M, mwM[(hb + s) * 10 + q]);
    float l = 0.f, o = 0.f;
    for (int s = 0; s < 16; s++) {
        const float a = __expf(mwM[(hb + s) * 10 + q] - M);
        l += a * mwL[(hb + s) * 10 + q];
        o += a * mwO[((hb + s) * 10 + q) * 128 + d];
    }
    mwat[(size_t)bg * 256 + h * 128 + d] = o / l;
}

// mw output projection: mw_ = mix_wt[g] + attn@ww_o + ww_ob ; grid B*G x 128
__global__ __launch_bounds__(128)
void mwproj_kernel(const float* __restrict__ A, const float* __restrict__ mixwt,
                   const float* __restrict__ W, const float* __restrict__ bias,
                   float* __restrict__ Y)
{
    const int bg  = blockIdx.x;
    const int g   = bg % G_;
    const int tid = threadIdx.x;
    __shared__ float ar[256];
    ar[tid]       = A[(size_t)bg * 256 + tid];
    ar[tid + 128] = A[(size_t)bg * 256 + tid + 128];
    __syncthreads();
    float acc = mixwt[g * 128 + tid] + bias[tid];
    #pragma unroll 8
    for (int i = 0; i < 256; i++)
        acc += ar[i] * W[i * 128 + tid];
    Y[(size_t)bg * 128 + tid] = acc;
}

__global__ __launch_bounds__(64)
void mwfinal_kernel(const float* __restrict__ MW, const float* __restrict__ wmix,
                    const float* __restrict__ bmix, float* __restrict__ out)
{
    const int b = blockIdx.x;
    const int g = threadIdx.x;
    __shared__ float z[16];
    if (g < G_) {
        float acc = bmix[0];
        for (int i = 0; i < 128; i++)
            acc += MW[((size_t)b * G_ + g) * 128 + i] * wmix[i];
        z[g] = acc;
    }
    __syncthreads();
    if (g == 0) {
        float mx = -3.4e38f;
        for (int i = 0; i < G_; i++) mx = fmaxf(mx, z[i]);
        float e[G_]; float s = 0.f;
        for (int i = 0; i < G_; i++) { e[i] = __expf(z[i] - mx); s += e[i]; }
        for (int i = 0; i < G_; i++) out[b * G_ + i] = e[i] / s;
    }
}

// ---------------------------------------------------------------------------
extern "C" void kernel_launch(void* const* d_in, const int* in_sizes, int n_in,
                              void* d_out, int out_size, void* d_ws, size_t ws_size,
                              hipStream_t stream)
{
    const float* obs    = (const float*)d_in[0];
    const float* mobs   = (const float*)d_in[1];
    const float* xq     = (const float*)d_in[2];
    const float* mq     = (const float*)d_in[3];
    const float* w_q0   = (const float*)d_in[4];
    const float* b_q0   = (const float*)d_in[5];
    const float* w_q1   = (const float*)d_in[6];
    const float* b_q1   = (const float*)d_in[7];
    const float* w_o0   = (const float*)d_in[8];
    const float* b_o0   = (const float*)d_in[9];
    const float* w_o1   = (const float*)d_in[10];
    const float* b_o1   = (const float*)d_in[11];
    const float* w_cobs = (const float*)d_in[12];
    const float* b_cobs = (const float*)d_in[13];
    const float* w_cq   = (const float*)d_in[14];
    const float* b_cq   = (const float*)d_in[15];
    const float* w_qp   = (const float*)d_in[16];
    const float* b_qp   = (const float*)d_in[17];
    const float* w_kp   = (const float*)d_in[18];
    const float* b_kp   = (const float*)d_in[19];
    const float* ws_q   = (const float*)d_in[20];
    const float* ws_qb  = (const float*)d_in[21];
    const float* ws_o   = (const float*)d_in[22];
    const float* ws_ob  = (const float*)d_in[23];
    const float* ww_q   = (const float*)d_in[24];
    const float* ww_qb  = (const float*)d_in[25];
    const float* ww_o   = (const float*)d_in[26];
    const float* ww_ob  = (const float*)d_in[27];
    const float* wc_q   = (const float*)d_in[28];
    const float* wc_qb  = (const float*)d_in[29];
    const float* wc_o   = (const float*)d_in[30];
    const float* wc_ob  = (const float*)d_in[31];
    const float* w_split= (const float*)d_in[32];
    const float* b_split= (const float*)d_in[33];
    const float* mix_wt = (const float*)d_in[34];
    const float* w_mix  = (const float*)d_in[35];
    const float* b_mix  = (const float*)d_in[36];

    float* out = (float*)d_out;
    char* ws  = (char*)d_ws;

    const size_t MB = (size_t)1 << 20;
    const size_t KB = (size_t)1 << 10;
    if (ws_size < 31 * MB + 512 * KB) return;

    const int NROW = B_ * L_;          // 8192
    bf16* featq = (bf16*)(ws + 0);                 // 4 MB  -> kvbs -> qcb
    bf16* feato = (bf16*)(ws + 4 * MB);            // 4.5 MB -> kvcb
    bf16* qe_bf = (bf16*)(ws + 8 * MB + 512 * KB); // 2 MB
    bf16* oe_bf = (bf16*)(ws + 10 * MB + 512 * KB);// 2 MB
    bf16* abuf  = (bf16*)(ws + 12 * MB + 512 * KB);// 4 MB -> abuf2
    bf16* x_bf  = (bf16*)(ws + 16 * MB + 512 * KB);// 2 MB
    bf16* x2_bf = (bf16*)(ws + 18 * MB + 512 * KB);// 2 MB
    bf16* kvmw  = (bf16*)(ws + 20 * MB + 512 * KB);// 4 MB
    char* wbase = ws + 24 * MB + 512 * KB;
    bf16* wqpT  = (bf16*)(wbase + 0);              // 64 KB (128 x 256)
    bf16* wkpT  = (bf16*)(wbase + 64 * KB);        // 72 KB (128 x 288)
    bf16* wsqT  = (bf16*)(wbase + 136 * KB);       // 64 KB (256 x 128)
    bf16* wsoT  = (bf16*)(wbase + 200 * KB);       // 64 KB (128 x 256)
    bf16* wwqT  = (bf16*)(wbase + 264 * KB);       // 64 KB
    bf16* wcqT  = (bf16*)(wbase + 328 * KB);       // 64 KB
    bf16* wcoT  = (bf16*)(wbase + 392 * KB);       // 64 KB
    bf16* wsplT = (bf16*)(wbase + 456 * KB);       // 320 KB (1280 x 128)
    bf16* qmwb  = (bf16*)(wbase + 776 * KB);       // 8 KB (2,16,128)
    float* mwO  = (float*)(wbase + 784 * KB);      // 640 KB
    float* mwM  = (float*)(wbase + 1424 * KB);     // 5 KB
    float* mwL  = (float*)(wbase + 1432 * KB);     // 5 KB
    float* mwat = (float*)(wbase + 1440 * KB);     // 40 KB
    float* mw_  = (float*)(wbase + 1480 * KB);     // 20 KB
    bf16* kvT   = (bf16*)(ws + 27 * MB + 512 * KB);// 4 MB (BH,H,L), self then cross
    bf16* kvbs  = featq;
    bf16* qcb   = featq;
    bf16* kvcb  = feato;
    bf16* abuf2 = abuf;

    // 0: all weight transposes in one launch
    WtArgs wa;
    wa.W[0]=w_qp;   wa.T[0]=wqpT;  wa.K[0]=256; wa.Kp[0]=256; wa.N[0]=128;
    wa.W[1]=w_kp;   wa.T[1]=wkpT;  wa.K[1]=257; wa.Kp[1]=288; wa.N[1]=128;
    wa.W[2]=ws_q;   wa.T[2]=wsqT;  wa.K[2]=128; wa.Kp[2]=128; wa.N[2]=256;
    wa.W[3]=ws_o;   wa.T[3]=wsoT;  wa.K[3]=256; wa.Kp[3]=256; wa.N[3]=128;
    wa.W[4]=ww_q;   wa.T[4]=wwqT;  wa.K[4]=128; wa.Kp[4]=128; wa.N[4]=256;
    wa.W[5]=wc_q;   wa.T[5]=wcqT;  wa.K[5]=128; wa.Kp[5]=128; wa.N[5]=256;
    wa.W[6]=wc_o;   wa.T[6]=wcoT;  wa.K[6]=256; wa.Kp[6]=256; wa.N[6]=128;
    wa.W[7]=w_split;wa.T[7]=wsplT; wa.K[7]=128; wa.Kp[7]=128; wa.N[7]=1280;
    wtrans_all_kernel<<<dim3(1280, 8), 288, 0, stream>>>(wa);

    // 1-2: featurize
    featq_kernel<<<NROW, 128, 0, stream>>>(xq, mq, w_q0, b_q0, w_q1, b_q1,
                                           w_cq, b_cq, featq);
    feato_kernel<<<NROW, 128, 0, stream>>>(obs, mobs, w_o0, b_o0, w_o1, b_o1,
                                           w_cobs, b_cobs, feato);
    // 3-4: embed projections (MFMA)
    gemm_kernel<<<dim3(NROW/64, 2), 256, 0, stream>>>(featq, wqpT, b_qp, nullptr,
                                                      qe_bf, 256, 128, 1, 0);
    gemm_kernel<<<dim3(NROW/64, 2), 256, 0, stream>>>(feato, wkpT, b_kp, nullptr,
                                                      oe_bf, 288, 128, 1, 0);
    // 5: self-attn shared q=k=v projection (per-head bf16) + transpose
    gemm_kernel<<<dim3(NROW/64, 4), 256, 0, stream>>>(oe_bf, wsqT, ws_qb, nullptr,
                                                      kvbs, 128, 256, 2, 0);
    kvtrans_kernel<<<dim3(L_/64, B_*NH_), 256, 0, stream>>>(kvbs, kvT);
    // 6: self attention (barrier-free flash)
    flash_attn_kernel<<<dim3(B_*NH_, L_/64), 512, 0, stream>>>(kvbs, kvbs, kvT,
                                                               nullptr, mobs, abuf);
    // 7: x = relu(oe + attn @ ws_o + ws_ob)
    gemm_kernel<<<dim3(NROW/64, 2), 256, 0, stream>>>(abuf, wsoT, ws_ob, oe_bf,
                                                      x_bf, 256, 128, 1, 1);
    // 8-13: mixing-weights path
    qmwb_kernel<<<16, 256, 0, stream>>>(mix_wt, ww_q, ww_qb, qmwb);
    gemm_kernel<<<dim3(NROW/64, 4), 256, 0, stream>>>(x_bf, wwqT, ww_qb, nullptr,
                                                      kvmw, 128, 256, 2, 0);
    mwpartial_kernel<<<dim3(16, NH_, B_), 256, 0, stream>>>(qmwb, kvmw, mobs,
                                                            mwO, mwM, mwL);
    mwcombine_kernel<<<B_ * G_, 256, 0, stream>>>(mwO, mwM, mwL, mwat);
    mwproj_kernel<<<B_ * G_, 128, 0, stream>>>(mwat, mix_wt, ww_o, ww_ob, mw_);
    mwfinal_kernel<<<B_, 64, 0, stream>>>(mw_, w_mix, b_mix,
                                          out + (size_t)B_ * G_ * L_ * H_);
    // 14-15: cross-attn projections (k==v share one projection) + transpose
    gemm_kernel<<<dim3(NROW/64, 4), 256, 0, stream>>>(qe_bf, wcqT, wc_qb, nullptr,
                                                      qcb, 128, 256, 2, 0);
    gemm_kernel<<<dim3(NROW/64, 4), 256, 0, stream>>>(x_bf, wcqT, wc_qb, nullptr,
                                                      kvcb, 128, 256, 2, 0);
    kvtrans_kernel<<<dim3(L_/64, B_*NH_), 256, 0, stream>>>(kvcb, kvT);
    // 16: cross attention
    flash_attn_kernel<<<dim3(B_*NH_, L_/64), 512, 0, stream>>>(qcb, kvcb, kvT,
                                                               mq, mobs, abuf2);
    // 17: x2 = relu(qe + attn2 @ wc_o + wc_ob)
    gemm_kernel<<<dim3(NROW/64, 2), 256, 0, stream>>>(abuf2, wcoT, wc_ob, qe_bf,
                                                      x2_bf, 256, 128, 1, 1);
    // 18: split + transpose store (MFMA)
    gemm_kernel<<<dim3(NROW/64, 20), 256, 0, stream>>>(x2_bf, wsplT, b_split, nullptr,
                                                       out, 128, 1280, 3, 0);

    (void)in_sizes; (void)n_in; (void)out_size;
}